// Round 3
// baseline (357.172 us; speedup 1.0000x reference)
//
#include <hip/hip_runtime.h>
#include <math.h>

#define N 4096
#define P 128
#define LDIM 32

typedef unsigned int u32;
typedef unsigned short u16;
typedef short s16x8 __attribute__((ext_vector_type(8)));
typedef float f32x4 __attribute__((ext_vector_type(4)));

// ---------- bf16 helpers (RNE) ----------
__device__ __forceinline__ u16 f2b(float f) {
  u32 u = __float_as_uint(f);
  u += 0x7fffu + ((u >> 16) & 1u);
  return (u16)(u >> 16);
}
__device__ __forceinline__ float b2f(u16 h) { return __uint_as_float(((u32)h) << 16); }

// ---------- weight functions (match reference) ----------
__device__ __forceinline__ float w1f(float d, float r) {
  if (d < r) { float t = d / r; float b = 1.0f - t * t; return b * b * b; }
  return 0.0f;
}
__device__ __forceinline__ float w2f(float d, float r) {
  if (d < 0.5f * r) return 1.0f;
  if (d < r) { float t = (2.0f * d - r) / r; float b = 1.0f - t * t; return b * b * b; }
  return 0.0f;
}
__device__ __forceinline__ float geluf(float a) {
  return 0.5f * a * (1.0f + erff(a * 0.70710678118654752f));
}

#define MFMA(a, b, c) __builtin_amdgcn_mfma_f32_16x16x32_bf16((a), (b), (c), 0, 0, 0)

// ---------- K0: zero accumulators + out ----------
__global__ __launch_bounds__(256) void k_init(float* __restrict__ z, int cnt, float* __restrict__ out) {
  int i = blockIdx.x * 256 + threadIdx.x;
  if (i < cnt) z[i] = 0.0f;
  if (blockIdx.x == 0 && threadIdx.x == 0) out[0] = 0.0f;
}

// ---------- K1: xb = bf16(x), xbT = transpose, x2 from bf16 values ----------
__global__ __launch_bounds__(256) void k_prep(const float* __restrict__ x, u16* __restrict__ xb,
                                              u16* __restrict__ xbT, float* __restrict__ x2) {
  __shared__ u16 tl[32][36];
  const int bi = blockIdx.x * 32, bk = blockIdx.y * 32;
  const int tid = threadIdx.x;
  const int row = tid >> 3, cs = (tid & 7) * 4;
  float4 v = *(const float4*)&x[(size_t)(bi + row) * P + bk + cs];
  u16 h0 = f2b(v.x), h1 = f2b(v.y), h2 = f2b(v.z), h3 = f2b(v.w);
  float d0 = b2f(h0), d1 = b2f(h1), d2 = b2f(h2), d3 = b2f(h3);
  float s = d0 * d0 + d1 * d1 + d2 * d2 + d3 * d3;  // norms from bf16-rounded values (cancellation consistency)
  s += __shfl_down(s, 4); s += __shfl_down(s, 2); s += __shfl_down(s, 1);
  if ((tid & 7) == 0) atomicAdd(&x2[bi + row], s);
  ushort4 o4; o4.x = h0; o4.y = h1; o4.z = h2; o4.w = h3;
  *(ushort4*)(xb + (size_t)(bi + row) * P + bk + cs) = o4;
  tl[row][cs + 0] = h0; tl[row][cs + 1] = h1; tl[row][cs + 2] = h2; tl[row][cs + 3] = h3;
  __syncthreads();
  const int orow = tid >> 3, ocs = (tid & 7) * 4;
  ushort4 t4;
  t4.x = tl[ocs + 0][orow]; t4.y = tl[ocs + 1][orow]; t4.z = tl[ocs + 2][orow]; t4.w = tl[ocs + 3][orow];
  *(ushort4*)(xbT + (size_t)(bk + orow) * N + bi + ocs) = t4;
}

// ---------- K2: dist (bf16) via MFMA xb@xbT + atomic max ----------
__global__ __launch_bounds__(256) void k_dist(const u16* __restrict__ xb, const float* __restrict__ x2,
                                              u16* __restrict__ dist, u32* __restrict__ mdb) {
  __shared__ uint4 L[4096];  // A: [0..2047], B: [2048..4095]; reused as 128x136 u16 out tile
  const int bi = blockIdx.y * 128, bj = blockIdx.x * 128;
  const int tid = threadIdx.x;
  const int lane = tid & 63, wv = tid >> 6;
  const int wi = wv >> 1, wj = wv & 1;
  const int lm = lane & 15, quad = lane >> 4;
  const uint4* ga = (const uint4*)(xb + (size_t)bi * P);
  const uint4* gb = (const uint4*)(xb + (size_t)bj * P);
#pragma unroll
  for (int it = 0; it < 8; ++it) {
    int c = it * 256 + tid;
    int row = c >> 4, ch = c & 15;
    int sw = row * 16 + (ch ^ (row & 7));
    L[sw] = ga[c];
    L[2048 + sw] = gb[c];
  }
  __syncthreads();
  f32x4 acc[4][4];
#pragma unroll
  for (int u = 0; u < 4; u++)
#pragma unroll
    for (int v = 0; v < 4; v++) acc[u][v] = {0.f, 0.f, 0.f, 0.f};
#pragma unroll
  for (int ks = 0; ks < 4; ++ks) {
    s16x8 af[4], bf[4];
#pragma unroll
    for (int u = 0; u < 4; u++) { int r = wi * 64 + u * 16 + lm; af[u] = *(const s16x8*)&L[r * 16 + ((ks * 4 + quad) ^ (r & 7))]; }
#pragma unroll
    for (int v = 0; v < 4; v++) { int r = wj * 64 + v * 16 + lm; bf[v] = *(const s16x8*)&L[2048 + r * 16 + ((ks * 4 + quad) ^ (r & 7))]; }
#pragma unroll
    for (int u = 0; u < 4; u++)
#pragma unroll
      for (int v = 0; v < 4; v++) acc[u][v] = MFMA(af[u], bf[v], acc[u][v]);
  }
  __syncthreads();
  u16* outl = (u16*)L;  // [128][136]
  float lmax = 0.0f;
#pragma unroll
  for (int u = 0; u < 4; u++)
#pragma unroll
    for (int v = 0; v < 4; v++) {
      int col = wj * 64 + v * 16 + lm;
      float xjc = x2[bj + col];
#pragma unroll
      for (int reg = 0; reg < 4; reg++) {
        int row = wi * 64 + u * 16 + quad * 4 + reg;
        float d2 = x2[bi + row] + xjc - 2.0f * acc[u][v][reg];
        float d = sqrtf(fmaxf(d2, 1e-12f));
        lmax = fmaxf(lmax, d);
        outl[row * 136 + col] = f2b(d);
      }
    }
#pragma unroll
  for (int o = 32; o > 0; o >>= 1) lmax = fmaxf(lmax, __shfl_down(lmax, o));
  if (lane == 0) atomicMax(mdb, __float_as_uint(lmax));
  __syncthreads();
#pragma unroll
  for (int it = 0; it < 8; ++it) {
    int c = it * 256 + tid;
    int row = c >> 4, ch = c & 15;
    uint4 v = *(const uint4*)&outl[row * 136 + ch * 8];
    *(uint4*)(dist + (size_t)(bi + row) * N + bj + ch * 8) = v;
  }
}

// ---------- pack transform for Wtx staging ----------
template <int MODE>
__device__ __forceinline__ u32 procpack(u32 pk, float r, float& s) {
  float lo = b2f((u16)(pk & 0xffffu));
  float hi = b2f((u16)(pk >> 16));
  if (MODE == 0) {
    u16 l2 = f2b(w1f(lo, r)), h2 = f2b(w1f(hi, r));
    lo = b2f(l2); hi = b2f(h2);
    pk = (u32)l2 | ((u32)h2 << 16);
  }
  s += lo + hi;
  return pk;
}

// ---------- K3/K6: C[j,:] += sum_i A[j,i]*x[i,:]  (MODE0: A=w1(dist), symmetric; MODE1: A=betaT) ----------
// fuses S[j] = sum_i A[j,i]
template <int MODE>
__global__ __launch_bounds__(256) void k_wtx(const u16* __restrict__ Wm, const u16* __restrict__ xbT,
                                             float* __restrict__ accout, float* __restrict__ Ssum,
                                             const float* __restrict__ rp, const u32* __restrict__ mdb) {
  __shared__ uint4 LA[640];  // 128 rows x 5 uint4 (64B data + 16B pad)
  __shared__ uint4 LB[640];
  const int j0 = blockIdx.x * 128;
  const int K0 = blockIdx.y * 256;
  const int tid = threadIdx.x;
  const int lane = tid & 63, wv = tid >> 6;
  const int wi = wv >> 1, wj = wv & 1;
  const int lm = lane & 15, quad = lane >> 4;
  float r = 0.0f;
  if (MODE == 0) r = fminf(rp[0], __uint_as_float(*mdb));
  const int srow = tid >> 1, half = tid & 1;
  float spart = 0.0f;
  f32x4 acc[4][4];
#pragma unroll
  for (int u = 0; u < 4; u++)
#pragma unroll
    for (int v = 0; v < 4; v++) acc[u][v] = {0.f, 0.f, 0.f, 0.f};
  for (int kc = 0; kc < 8; ++kc) {
    const int ic = K0 + kc * 32;
    {
      const uint4* p = (const uint4*)(Wm + (size_t)(j0 + srow) * N + ic + half * 16);
      uint4 a0 = p[0], a1 = p[1];
      a0.x = procpack<MODE>(a0.x, r, spart); a0.y = procpack<MODE>(a0.y, r, spart);
      a0.z = procpack<MODE>(a0.z, r, spart); a0.w = procpack<MODE>(a0.w, r, spart);
      a1.x = procpack<MODE>(a1.x, r, spart); a1.y = procpack<MODE>(a1.y, r, spart);
      a1.z = procpack<MODE>(a1.z, r, spart); a1.w = procpack<MODE>(a1.w, r, spart);
      LA[srow * 5 + half * 2 + 0] = a0;
      LA[srow * 5 + half * 2 + 1] = a1;
    }
    {
      const uint4* p = (const uint4*)(xbT + (size_t)srow * N + ic + half * 16);
      LB[srow * 5 + half * 2 + 0] = p[0];
      LB[srow * 5 + half * 2 + 1] = p[1];
    }
    __syncthreads();
    s16x8 af[4], bf[4];
#pragma unroll
    for (int u = 0; u < 4; u++) af[u] = *(const s16x8*)&LA[(wi * 64 + u * 16 + lm) * 5 + quad];
#pragma unroll
    for (int v = 0; v < 4; v++) bf[v] = *(const s16x8*)&LB[(wj * 64 + v * 16 + lm) * 5 + quad];
#pragma unroll
    for (int u = 0; u < 4; u++)
#pragma unroll
      for (int v = 0; v < 4; v++) acc[u][v] = MFMA(af[u], bf[v], acc[u][v]);
    __syncthreads();
  }
  atomicAdd(&Ssum[j0 + srow], spart);
#pragma unroll
  for (int u = 0; u < 4; u++)
#pragma unroll
    for (int v = 0; v < 4; v++) {
      int col = wj * 64 + v * 16 + lm;
#pragma unroll
      for (int reg = 0; reg < 4; reg++) {
        int row = wi * 64 + u * 16 + quad * 4 + reg;
        atomicAdd(&accout[(size_t)(j0 + row) * P + col], acc[u][v][reg]);
      }
    }
}

// ---------- K4: U finalize (guarded), Ub=bf16(U), u2,cj from bf16; zero muacc for ez reuse ----------
__global__ __launch_bounds__(128) void k_finU(const float* __restrict__ x, const u16* __restrict__ xb,
                                              float* __restrict__ muacc, const float* __restrict__ S1,
                                              u16* __restrict__ Ub, float* __restrict__ u2, float* __restrict__ cj) {
  const int j = blockIdx.x, t = threadIdx.x;
  float s = S1[j];
  float xv = x[(size_t)j * P + t];
  float uval = 0.0f;
  if (s > 0.0f) uval = xv - muacc[(size_t)j * P + t] / s;  // s==0 -> mu NaN -> mu=y -> U=0
  muacc[(size_t)j * P + t] = 0.0f;                          // recycle buffer as ezacc
  u16 ub = f2b(uval);
  Ub[(size_t)j * P + t] = ub;
  float uf = b2f(ub);
  float xbf = b2f(xb[(size_t)j * P + t]);
  float a = uf * uf, b = xbf * uf;
#pragma unroll
  for (int o = 32; o > 0; o >>= 1) { a += __shfl_down(a, o); b += __shfl_down(b, o); }
  __shared__ float ra[2], rb[2];
  if ((t & 63) == 0) { ra[t >> 6] = a; rb[t >> 6] = b; }
  __syncthreads();
  if (t == 0) { u2[j] = ra[0] + ra[1]; cj[j] = rb[0] + rb[1]; }
}

// ---------- K5: betaT (bf16) via MFMA ps = xb@UbT + fused weight2 epilogue, transposed store ----------
__global__ __launch_bounds__(256) void k_beta(const u16* __restrict__ xb, const u16* __restrict__ Ub,
                                              const float* __restrict__ u2, const float* __restrict__ cj,
                                              const u16* __restrict__ dist, u16* __restrict__ betaT,
                                              const float* __restrict__ r1p, const float* __restrict__ r2p,
                                              const u32* __restrict__ mdb) {
  __shared__ uint4 L[4096];
  const int bi = blockIdx.y * 128, bj = blockIdx.x * 128;
  const int tid = threadIdx.x;
  const int lane = tid & 63, wv = tid >> 6;
  const int wi = wv >> 1, wj = wv & 1;
  const int lm = lane & 15, quad = lane >> 4;
  const uint4* ga = (const uint4*)(xb + (size_t)bi * P);
  const uint4* gb = (const uint4*)(Ub + (size_t)bj * P);
#pragma unroll
  for (int it = 0; it < 8; ++it) {
    int c = it * 256 + tid;
    int row = c >> 4, ch = c & 15;
    int sw = row * 16 + (ch ^ (row & 7));
    L[sw] = ga[c];
    L[2048 + sw] = gb[c];
  }
  __syncthreads();
  f32x4 acc[4][4];
#pragma unroll
  for (int u = 0; u < 4; u++)
#pragma unroll
    for (int v = 0; v < 4; v++) acc[u][v] = {0.f, 0.f, 0.f, 0.f};
#pragma unroll
  for (int ks = 0; ks < 4; ++ks) {
    s16x8 af[4], bf[4];
#pragma unroll
    for (int u = 0; u < 4; u++) { int rr = wi * 64 + u * 16 + lm; af[u] = *(const s16x8*)&L[rr * 16 + ((ks * 4 + quad) ^ (rr & 7))]; }
#pragma unroll
    for (int v = 0; v < 4; v++) { int rr = wj * 64 + v * 16 + lm; bf[v] = *(const s16x8*)&L[2048 + rr * 16 + ((ks * 4 + quad) ^ (rr & 7))]; }
#pragma unroll
    for (int u = 0; u < 4; u++)
#pragma unroll
      for (int v = 0; v < 4; v++) acc[u][v] = MFMA(af[u], bf[v], acc[u][v]);
  }
  __syncthreads();
  const float md = __uint_as_float(*mdb);
  const float r1e = fminf(r1p[0], md), r2e = fminf(r2p[0], md);
  u16* outl = (u16*)L;  // transposed tile [j_local 128][i_local 136]
#pragma unroll
  for (int v = 0; v < 4; v++) {
    int col = wj * 64 + v * 16 + lm;
    float cjv = cj[bj + col];
    float u2v = u2[bj + col];
#pragma unroll
    for (int u = 0; u < 4; u++)
#pragma unroll
      for (int reg = 0; reg < 4; reg++) {
        int row = wi * 64 + u * 16 + quad * 4 + reg;
        float d = b2f(dist[(size_t)(bi + row) * N + bj + col]);
        float ps = acc[u][v][reg] - cjv;
        float du2 = fmaxf(ps * ps * u2v, 1e-6f);
        float dvv = sqrtf(fmaxf(d * d - du2, 1e-6f));
        float du = sqrtf(du2);
        outl[col * 136 + row] = f2b(w2f(dvv, r1e) * w2f(du, r2e));
      }
  }
  __syncthreads();
#pragma unroll
  for (int it = 0; it < 8; ++it) {
    int c = it * 256 + tid;
    int jl = c >> 4, ch = c & 15;
    uint4 v = *(const uint4*)&outl[jl * 136 + ch * 8];
    *(uint4*)(betaT + (size_t)(bj + jl) * N + bi + ch * 8) = v;
  }
}

// ---------- K7: e_Z normalize + autoencoder + MSE (16 rows/block, weights in LDS) ----------
#define AE_ROWS 16
__global__ __launch_bounds__(256) void k_ae(const float* __restrict__ x, const float* __restrict__ ezacc,
                                            const float* __restrict__ S2,
                                            const float* __restrict__ We1, const float* __restrict__ be1,
                                            const float* __restrict__ We2, const float* __restrict__ be2,
                                            const float* __restrict__ Wd1, const float* __restrict__ bd1,
                                            const float* __restrict__ Wd2, const float* __restrict__ bd2,
                                            float* __restrict__ out) {
  __shared__ float We1T[P][33];      // [k][o], padded: layer-1 lanes read distinct banks
  __shared__ float We2T[LDIM][33];
  __shared__ float Wd1T[LDIM][33];
  __shared__ float Wd2T[LDIM][129];  // [k][o], o in 0..127
  __shared__ float ezs[AE_ROWS][P];
  __shared__ float h1s[AE_ROWS][LDIM], zbs[AE_ROWS][LDIM], h2s[AE_ROWS][LDIM];
  __shared__ float be1s[LDIM], be2s[LDIM], bd1s[LDIM], bd2s[P];
  const int tid = threadIdx.x;
  const int r0 = blockIdx.x * AE_ROWS;
  for (int idx = tid; idx < P * LDIM; idx += 256) {
    int o = idx >> 7, k = idx & 127;
    We1T[k][o] = We1[idx];                 // We1 is [L][P] row-major
    int o2 = idx >> 5, k2 = idx & 31;
    Wd2T[k2][o2] = Wd2[idx];               // Wd2 is [P][L] row-major
  }
  for (int idx = tid; idx < LDIM * LDIM; idx += 256) {
    int o = idx >> 5, k = idx & 31;
    We2T[k][o] = We2[idx];
    Wd1T[k][o] = Wd1[idx];
  }
  if (tid < LDIM) { be1s[tid] = be1[tid]; be2s[tid] = be2[tid]; bd1s[tid] = bd1[tid]; }
  if (tid < P) bd2s[tid] = bd2[tid];
  for (int idx = tid; idx < AE_ROWS * P; idx += 256) {
    int r = idx >> 7, c = idx & 127;
    int row = r0 + r;
    float s2 = S2[row];
    float xv = x[(size_t)row * P + c];
    ezs[r][c] = (s2 > 0.0f) ? (ezacc[(size_t)row * P + c] / s2) : xv;
  }
  __syncthreads();
  // Layer 1: 16x32 outputs, dot len 128 -> 2 per thread
  {
    const int o = tid & 31, rh = tid >> 5;
#pragma unroll
    for (int rr = 0; rr < 2; rr++) {
      int r = rh + rr * 8;
      float a = be1s[o];
#pragma unroll 8
      for (int k = 0; k < P; k++) a = fmaf(We1T[k][o], ezs[r][k], a);
      h1s[r][o] = geluf(a);
    }
  }
  __syncthreads();
  // Layer 2: 16x32 outputs, dot len 32
  {
    const int o = tid & 31, rh = tid >> 5;
#pragma unroll
    for (int rr = 0; rr < 2; rr++) {
      int r = rh + rr * 8;
      float a = be2s[o];
#pragma unroll
      for (int k = 0; k < LDIM; k++) a = fmaf(We2T[k][o], h1s[r][k], a);
      zbs[r][o] = a;
    }
  }
  __syncthreads();
  // Layer 3: 16x32 outputs, dot len 32, gelu
  {
    const int o = tid & 31, rh = tid >> 5;
#pragma unroll
    for (int rr = 0; rr < 2; rr++) {
      int r = rh + rr * 8;
      float a = bd1s[o];
#pragma unroll
      for (int k = 0; k < LDIM; k++) a = fmaf(Wd1T[k][o], zbs[r][k], a);
      h2s[r][o] = geluf(a);
    }
  }
  __syncthreads();
  // Layer 4 + sigmoid + MSE: 16x128 outputs, dot len 32 -> 8 per thread
  {
    const int o = tid & 127, rh = tid >> 7;
    float part = 0.0f;
#pragma unroll
    for (int rr = 0; rr < 8; rr++) {
      int r = rh + rr * 2;
      int row = r0 + r;
      float a = bd2s[o];
#pragma unroll
      for (int k = 0; k < LDIM; k++) a = fmaf(Wd2T[k][o], h2s[r][k], a);
      float xh = 1.0f / (1.0f + expf(-a));
      float diff = x[(size_t)row * P + o] - xh;
      part = fmaf(diff, diff, part);
    }
#pragma unroll
    for (int off = 32; off > 0; off >>= 1) part += __shfl_down(part, off);
    if ((tid & 63) == 0) atomicAdd(out, part * (1.0f / ((float)N * (float)P)));
  }
}

extern "C" void kernel_launch(void* const* d_in, const int* in_sizes, int n_in,
                              void* d_out, int out_size, void* d_ws, size_t ws_size,
                              hipStream_t stream) {
  const float* x   = (const float*)d_in[0];
  const float* r0  = (const float*)d_in[1];
  const float* r1  = (const float*)d_in[2];
  const float* r2  = (const float*)d_in[3];
  const float* We1 = (const float*)d_in[4];
  const float* be1 = (const float*)d_in[5];
  const float* We2 = (const float*)d_in[6];
  const float* be2 = (const float*)d_in[7];
  const float* Wd1 = (const float*)d_in[8];
  const float* bd1 = (const float*)d_in[9];
  const float* Wd2 = (const float*)d_in[10];
  const float* bd2 = (const float*)d_in[11];
  float* out = (float*)d_out;

  char* base = (char*)d_ws;
  u16* dist   = (u16*)base;                  // 33554432 B
  u16* betaT  = (u16*)(base + 33554432);     // 33554432 B
  u16* xb     = (u16*)(base + 67108864);     // 1048576 B
  u16* xbT    = (u16*)(base + 68157440);     // 1048576 B
  u16* Ub     = (u16*)(base + 69205888);     // 1048576 B
  float* muacc = (float*)(base + 70254464);  // 2097152 B (recycled as ezacc after k_finU)
  float* x2   = muacc + (size_t)N * P;       // N floats  <- contiguous zero region starts at muacc
  float* S1   = x2 + N;
  float* S2   = S1 + N;
  u32* mdb    = (u32*)(S2 + N);              // 1 (inside zero region)
  float* u2   = (float*)(mdb + 1);           // written fully by k_finU
  float* cj   = u2 + N;
  float* ezacc = muacc;

  const int zcnt = N * P + 3 * N + 1;  // muacc + x2 + S1 + S2 + mdb
  hipLaunchKernelGGL(k_init, dim3((zcnt + 255) / 256), dim3(256), 0, stream, muacc, zcnt, out);
  hipLaunchKernelGGL(k_prep, dim3(N / 32, P / 32), dim3(256), 0, stream, x, xb, xbT, x2);
  hipLaunchKernelGGL(k_dist, dim3(N / 128, N / 128), dim3(256), 0, stream, xb, x2, dist, mdb);
  hipLaunchKernelGGL((k_wtx<0>), dim3(N / 128, 16), dim3(256), 0, stream, dist, xbT, muacc, S1, r0, mdb);
  hipLaunchKernelGGL(k_finU, dim3(N), dim3(128), 0, stream, x, xb, muacc, S1, Ub, u2, cj);
  hipLaunchKernelGGL(k_beta, dim3(N / 128, N / 128), dim3(256), 0, stream, xb, Ub, u2, cj, dist, betaT, r1, r2, mdb);
  hipLaunchKernelGGL((k_wtx<1>), dim3(N / 128, 16), dim3(256), 0, stream, betaT, xbT, ezacc, S2, r0, mdb);
  hipLaunchKernelGGL(k_ae, dim3(N / AE_ROWS), dim3(256), 0, stream, x, ezacc, S2, We1, be1, We2, be2, Wd1, bd1, Wd2, bd2, out);
}

// Round 4
// 295.430 us; speedup vs baseline: 1.2090x; 1.2090x over previous
//
#include <hip/hip_runtime.h>
#include <math.h>

#define N 4096
#define P 128
#define LDIM 32

typedef unsigned int u32;
typedef unsigned short u16;
typedef short s16x8 __attribute__((ext_vector_type(8)));
typedef float f32x4 __attribute__((ext_vector_type(4)));

// ---------- bf16 helpers (RNE) ----------
__device__ __forceinline__ u16 f2b(float f) {
  u32 u = __float_as_uint(f);
  u += 0x7fffu + ((u >> 16) & 1u);
  return (u16)(u >> 16);
}
__device__ __forceinline__ float b2f(u16 h) { return __uint_as_float(((u32)h) << 16); }

// ---------- weight functions (match reference) ----------
__device__ __forceinline__ float w1f(float d, float r) {
  if (d < r) { float t = d / r; float b = 1.0f - t * t; return b * b * b; }
  return 0.0f;
}
__device__ __forceinline__ float w2f(float d, float r) {
  if (d < 0.5f * r) return 1.0f;
  if (d < r) { float t = (2.0f * d - r) / r; float b = 1.0f - t * t; return b * b * b; }
  return 0.0f;
}
__device__ __forceinline__ float geluf(float a) {
  return 0.5f * a * (1.0f + erff(a * 0.70710678118654752f));
}

#define MFMA(a, b, c) __builtin_amdgcn_mfma_f32_16x16x32_bf16((a), (b), (c), 0, 0, 0)

// ---------- K0: zero accumulators + out ----------
__global__ __launch_bounds__(256) void k_init(float* __restrict__ z, int cnt, float* __restrict__ out) {
  int i = blockIdx.x * 256 + threadIdx.x;
  if (i < cnt) z[i] = 0.0f;
  if (blockIdx.x == 0 && threadIdx.x == 0) out[0] = 0.0f;
}

// ---------- K1: xb = bf16(x), xbT = transpose, x2 from bf16 values ----------
__global__ __launch_bounds__(256) void k_prep(const float* __restrict__ x, u16* __restrict__ xb,
                                              u16* __restrict__ xbT, float* __restrict__ x2) {
  __shared__ u16 tl[32][36];
  const int bi = blockIdx.x * 32, bk = blockIdx.y * 32;
  const int tid = threadIdx.x;
  const int row = tid >> 3, cs = (tid & 7) * 4;
  float4 v = *(const float4*)&x[(size_t)(bi + row) * P + bk + cs];
  u16 h0 = f2b(v.x), h1 = f2b(v.y), h2 = f2b(v.z), h3 = f2b(v.w);
  float d0 = b2f(h0), d1 = b2f(h1), d2 = b2f(h2), d3 = b2f(h3);
  float s = d0 * d0 + d1 * d1 + d2 * d2 + d3 * d3;  // norms from bf16-rounded values (cancellation consistency)
  s += __shfl_down(s, 4); s += __shfl_down(s, 2); s += __shfl_down(s, 1);
  if ((tid & 7) == 0) atomicAdd(&x2[bi + row], s);
  ushort4 o4; o4.x = h0; o4.y = h1; o4.z = h2; o4.w = h3;
  *(ushort4*)(xb + (size_t)(bi + row) * P + bk + cs) = o4;
  tl[row][cs + 0] = h0; tl[row][cs + 1] = h1; tl[row][cs + 2] = h2; tl[row][cs + 3] = h3;
  __syncthreads();
  const int orow = tid >> 3, ocs = (tid & 7) * 4;
  ushort4 t4;
  t4.x = tl[ocs + 0][orow]; t4.y = tl[ocs + 1][orow]; t4.z = tl[ocs + 2][orow]; t4.w = tl[ocs + 3][orow];
  *(ushort4*)(xbT + (size_t)(bk + orow) * N + bi + ocs) = t4;
}

// ---------- K2: dist (bf16) via MFMA xb@xbT + atomic max ----------
__global__ __launch_bounds__(256) void k_dist(const u16* __restrict__ xb, const float* __restrict__ x2,
                                              u16* __restrict__ dist, u32* __restrict__ mdb) {
  __shared__ uint4 L[4096];  // A: [0..2047], B: [2048..4095]; reused as 128x136 u16 out tile
  const int bi = blockIdx.y * 128, bj = blockIdx.x * 128;
  const int tid = threadIdx.x;
  const int lane = tid & 63, wv = tid >> 6;
  const int wi = wv >> 1, wj = wv & 1;
  const int lm = lane & 15, quad = lane >> 4;
  const uint4* ga = (const uint4*)(xb + (size_t)bi * P);
  const uint4* gb = (const uint4*)(xb + (size_t)bj * P);
#pragma unroll
  for (int it = 0; it < 8; ++it) {
    int c = it * 256 + tid;
    int row = c >> 4, ch = c & 15;
    int sw = row * 16 + (ch ^ (row & 7));
    L[sw] = ga[c];
    L[2048 + sw] = gb[c];
  }
  __syncthreads();
  f32x4 acc[4][4];
#pragma unroll
  for (int u = 0; u < 4; u++)
#pragma unroll
    for (int v = 0; v < 4; v++) acc[u][v] = {0.f, 0.f, 0.f, 0.f};
#pragma unroll
  for (int ks = 0; ks < 4; ++ks) {
    s16x8 af[4], bf[4];
#pragma unroll
    for (int u = 0; u < 4; u++) { int r = wi * 64 + u * 16 + lm; af[u] = *(const s16x8*)&L[r * 16 + ((ks * 4 + quad) ^ (r & 7))]; }
#pragma unroll
    for (int v = 0; v < 4; v++) { int r = wj * 64 + v * 16 + lm; bf[v] = *(const s16x8*)&L[2048 + r * 16 + ((ks * 4 + quad) ^ (r & 7))]; }
#pragma unroll
    for (int u = 0; u < 4; u++)
#pragma unroll
      for (int v = 0; v < 4; v++) acc[u][v] = MFMA(af[u], bf[v], acc[u][v]);
  }
  __syncthreads();
  u16* outl = (u16*)L;  // [128][136]
  float lmax = 0.0f;
#pragma unroll
  for (int u = 0; u < 4; u++)
#pragma unroll
    for (int v = 0; v < 4; v++) {
      int col = wj * 64 + v * 16 + lm;
      float xjc = x2[bj + col];
#pragma unroll
      for (int reg = 0; reg < 4; reg++) {
        int row = wi * 64 + u * 16 + quad * 4 + reg;
        float d2 = x2[bi + row] + xjc - 2.0f * acc[u][v][reg];
        float d = sqrtf(fmaxf(d2, 1e-12f));
        lmax = fmaxf(lmax, d);
        outl[row * 136 + col] = f2b(d);
      }
    }
#pragma unroll
  for (int o = 32; o > 0; o >>= 1) lmax = fmaxf(lmax, __shfl_down(lmax, o));
  if (lane == 0) atomicMax(mdb, __float_as_uint(lmax));
  __syncthreads();
#pragma unroll
  for (int it = 0; it < 8; ++it) {
    int c = it * 256 + tid;
    int row = c >> 4, ch = c & 15;
    uint4 v = *(const uint4*)&outl[row * 136 + ch * 8];
    *(uint4*)(dist + (size_t)(bi + row) * N + bj + ch * 8) = v;
  }
}

// ---------- pack transform for Wtx staging ----------
template <int MODE>
__device__ __forceinline__ u32 procpack(u32 pk, float r, float& s) {
  float lo = b2f((u16)(pk & 0xffffu));
  float hi = b2f((u16)(pk >> 16));
  if (MODE == 0) {
    u16 l2 = f2b(w1f(lo, r)), h2 = f2b(w1f(hi, r));
    lo = b2f(l2); hi = b2f(h2);
    pk = (u32)l2 | ((u32)h2 << 16);
  }
  s += lo + hi;
  return pk;
}

// ---------- K3/K6: C[j,:] += sum_i A[j,i]*x[i,:]  (MODE0: A=w1(dist), symmetric; MODE1: A=betaT) ----------
// fuses S[j] = sum_i A[j,i]
template <int MODE>
__global__ __launch_bounds__(256) void k_wtx(const u16* __restrict__ Wm, const u16* __restrict__ xbT,
                                             float* __restrict__ accout, float* __restrict__ Ssum,
                                             const float* __restrict__ rp, const u32* __restrict__ mdb) {
  __shared__ uint4 LA[640];  // 128 rows x 5 uint4 (64B data + 16B pad)
  __shared__ uint4 LB[640];
  const int j0 = blockIdx.x * 128;
  const int K0 = blockIdx.y * 256;
  const int tid = threadIdx.x;
  const int lane = tid & 63, wv = tid >> 6;
  const int wi = wv >> 1, wj = wv & 1;
  const int lm = lane & 15, quad = lane >> 4;
  float r = 0.0f;
  if (MODE == 0) r = fminf(rp[0], __uint_as_float(*mdb));
  const int srow = tid >> 1, half = tid & 1;
  float spart = 0.0f;
  f32x4 acc[4][4];
#pragma unroll
  for (int u = 0; u < 4; u++)
#pragma unroll
    for (int v = 0; v < 4; v++) acc[u][v] = {0.f, 0.f, 0.f, 0.f};
  for (int kc = 0; kc < 8; ++kc) {
    const int ic = K0 + kc * 32;
    {
      const uint4* p = (const uint4*)(Wm + (size_t)(j0 + srow) * N + ic + half * 16);
      uint4 a0 = p[0], a1 = p[1];
      a0.x = procpack<MODE>(a0.x, r, spart); a0.y = procpack<MODE>(a0.y, r, spart);
      a0.z = procpack<MODE>(a0.z, r, spart); a0.w = procpack<MODE>(a0.w, r, spart);
      a1.x = procpack<MODE>(a1.x, r, spart); a1.y = procpack<MODE>(a1.y, r, spart);
      a1.z = procpack<MODE>(a1.z, r, spart); a1.w = procpack<MODE>(a1.w, r, spart);
      LA[srow * 5 + half * 2 + 0] = a0;
      LA[srow * 5 + half * 2 + 1] = a1;
    }
    {
      const uint4* p = (const uint4*)(xbT + (size_t)srow * N + ic + half * 16);
      LB[srow * 5 + half * 2 + 0] = p[0];
      LB[srow * 5 + half * 2 + 1] = p[1];
    }
    __syncthreads();
    s16x8 af[4], bf[4];
#pragma unroll
    for (int u = 0; u < 4; u++) af[u] = *(const s16x8*)&LA[(wi * 64 + u * 16 + lm) * 5 + quad];
#pragma unroll
    for (int v = 0; v < 4; v++) bf[v] = *(const s16x8*)&LB[(wj * 64 + v * 16 + lm) * 5 + quad];
#pragma unroll
    for (int u = 0; u < 4; u++)
#pragma unroll
      for (int v = 0; v < 4; v++) acc[u][v] = MFMA(af[u], bf[v], acc[u][v]);
    __syncthreads();
  }
  atomicAdd(&Ssum[j0 + srow], spart);
#pragma unroll
  for (int u = 0; u < 4; u++)
#pragma unroll
    for (int v = 0; v < 4; v++) {
      int col = wj * 64 + v * 16 + lm;
#pragma unroll
      for (int reg = 0; reg < 4; reg++) {
        int row = wi * 64 + u * 16 + quad * 4 + reg;
        atomicAdd(&accout[(size_t)(j0 + row) * P + col], acc[u][v][reg]);
      }
    }
}

// ---------- K4: U finalize (guarded), Ub=bf16(U), u2,cj from bf16; zero muacc for ez reuse ----------
__global__ __launch_bounds__(128) void k_finU(const float* __restrict__ x, const u16* __restrict__ xb,
                                              float* __restrict__ muacc, const float* __restrict__ S1,
                                              u16* __restrict__ Ub, float* __restrict__ u2, float* __restrict__ cj) {
  const int j = blockIdx.x, t = threadIdx.x;
  float s = S1[j];
  float xv = x[(size_t)j * P + t];
  float uval = 0.0f;
  if (s > 0.0f) uval = xv - muacc[(size_t)j * P + t] / s;  // s==0 -> mu NaN -> mu=y -> U=0
  muacc[(size_t)j * P + t] = 0.0f;                          // recycle buffer as ezacc
  u16 ub = f2b(uval);
  Ub[(size_t)j * P + t] = ub;
  float uf = b2f(ub);
  float xbf = b2f(xb[(size_t)j * P + t]);
  float a = uf * uf, b = xbf * uf;
#pragma unroll
  for (int o = 32; o > 0; o >>= 1) { a += __shfl_down(a, o); b += __shfl_down(b, o); }
  __shared__ float ra[2], rb[2];
  if ((t & 63) == 0) { ra[t >> 6] = a; rb[t >> 6] = b; }
  __syncthreads();
  if (t == 0) { u2[j] = ra[0] + ra[1]; cj[j] = rb[0] + rb[1]; }
}

// ---------- K5: betaT (bf16). Two MFMA passes: G=xb@xbT (recompute d2, no dist read) and ps=xb@UbT. ----------
__global__ __launch_bounds__(256) void k_beta(const u16* __restrict__ xb, const u16* __restrict__ Ub,
                                              const float* __restrict__ x2,
                                              const float* __restrict__ u2, const float* __restrict__ cj,
                                              u16* __restrict__ betaT,
                                              const float* __restrict__ r1p, const float* __restrict__ r2p,
                                              const u32* __restrict__ mdb) {
  __shared__ uint4 L[4096];  // region0: A=xb_i tile; region1: B tile (xb_j then Ub_j); reused as out tile
  const int bi = blockIdx.y * 128, bj = blockIdx.x * 128;
  const int tid = threadIdx.x;
  const int lane = tid & 63, wv = tid >> 6;
  const int wi = wv >> 1, wj = wv & 1;
  const int lm = lane & 15, quad = lane >> 4;
  const uint4* ga = (const uint4*)(xb + (size_t)bi * P);
  const uint4* gb = (const uint4*)(xb + (size_t)bj * P);
  const uint4* gu = (const uint4*)(Ub + (size_t)bj * P);
#pragma unroll
  for (int it = 0; it < 8; ++it) {
    int c = it * 256 + tid;
    int row = c >> 4, ch = c & 15;
    int sw = row * 16 + (ch ^ (row & 7));
    L[sw] = ga[c];
    L[2048 + sw] = gb[c];
  }
  __syncthreads();
  f32x4 accG[4][4], accP[4][4];
#pragma unroll
  for (int u = 0; u < 4; u++)
#pragma unroll
    for (int v = 0; v < 4; v++) { accG[u][v] = {0.f, 0.f, 0.f, 0.f}; accP[u][v] = {0.f, 0.f, 0.f, 0.f}; }
  // pass 1: G = xb_i @ xb_j^T
#pragma unroll
  for (int ks = 0; ks < 4; ++ks) {
    s16x8 af[4], bf[4];
#pragma unroll
    for (int u = 0; u < 4; u++) { int rr = wi * 64 + u * 16 + lm; af[u] = *(const s16x8*)&L[rr * 16 + ((ks * 4 + quad) ^ (rr & 7))]; }
#pragma unroll
    for (int v = 0; v < 4; v++) { int rr = wj * 64 + v * 16 + lm; bf[v] = *(const s16x8*)&L[2048 + rr * 16 + ((ks * 4 + quad) ^ (rr & 7))]; }
#pragma unroll
    for (int u = 0; u < 4; u++)
#pragma unroll
      for (int v = 0; v < 4; v++) accG[u][v] = MFMA(af[u], bf[v], accG[u][v]);
  }
  __syncthreads();  // pass-1 LDS reads done before restaging region1
#pragma unroll
  for (int it = 0; it < 8; ++it) {
    int c = it * 256 + tid;
    int row = c >> 4, ch = c & 15;
    int sw = row * 16 + (ch ^ (row & 7));
    L[2048 + sw] = gu[c];
  }
  __syncthreads();
  // pass 2: ps = xb_i @ Ub_j^T
#pragma unroll
  for (int ks = 0; ks < 4; ++ks) {
    s16x8 af[4], bf[4];
#pragma unroll
    for (int u = 0; u < 4; u++) { int rr = wi * 64 + u * 16 + lm; af[u] = *(const s16x8*)&L[rr * 16 + ((ks * 4 + quad) ^ (rr & 7))]; }
#pragma unroll
    for (int v = 0; v < 4; v++) { int rr = wj * 64 + v * 16 + lm; bf[v] = *(const s16x8*)&L[2048 + rr * 16 + ((ks * 4 + quad) ^ (rr & 7))]; }
#pragma unroll
    for (int u = 0; u < 4; u++)
#pragma unroll
      for (int v = 0; v < 4; v++) accP[u][v] = MFMA(af[u], bf[v], accP[u][v]);
  }
  __syncthreads();
  const float md = __uint_as_float(*mdb);
  const float r1e = fminf(r1p[0], md), r2e = fminf(r2p[0], md);
  float xi[4][4];  // x2 for rows, [u][reg]
#pragma unroll
  for (int u = 0; u < 4; u++)
#pragma unroll
    for (int reg = 0; reg < 4; reg++) xi[u][reg] = x2[bi + wi * 64 + u * 16 + quad * 4 + reg];
  u16* outl = (u16*)L;  // transposed tile [j_local 128][i_local 136]
#pragma unroll
  for (int v = 0; v < 4; v++) {
    int col = wj * 64 + v * 16 + lm;
    float cjv = cj[bj + col];
    float u2v = u2[bj + col];
    float xjc = x2[bj + col];
#pragma unroll
    for (int u = 0; u < 4; u++)
#pragma unroll
      for (int reg = 0; reg < 4; reg++) {
        int row = wi * 64 + u * 16 + quad * 4 + reg;
        float d2 = fmaxf(xi[u][reg] + xjc - 2.0f * accG[u][v][reg], 1e-12f);
        float ps = accP[u][v][reg] - cjv;
        float du2 = fmaxf(ps * ps * u2v, 1e-6f);
        float dvv = sqrtf(fmaxf(d2 - du2, 1e-6f));
        float du = sqrtf(du2);
        outl[col * 136 + row] = f2b(w2f(dvv, r1e) * w2f(du, r2e));
      }
  }
  __syncthreads();
#pragma unroll
  for (int it = 0; it < 8; ++it) {
    int c = it * 256 + tid;
    int jl = c >> 4, ch = c & 15;
    uint4 v = *(const uint4*)&outl[jl * 136 + ch * 8];
    *(uint4*)(betaT + (size_t)(bj + jl) * N + bi + ch * 8) = v;
  }
}

// ---------- K7: e_Z normalize + autoencoder + MSE (16 rows/block, weights in LDS) ----------
#define AE_ROWS 16
__global__ __launch_bounds__(256) void k_ae(const float* __restrict__ x, const float* __restrict__ ezacc,
                                            const float* __restrict__ S2,
                                            const float* __restrict__ We1, const float* __restrict__ be1,
                                            const float* __restrict__ We2, const float* __restrict__ be2,
                                            const float* __restrict__ Wd1, const float* __restrict__ bd1,
                                            const float* __restrict__ Wd2, const float* __restrict__ bd2,
                                            float* __restrict__ out) {
  __shared__ float We1T[P][33];      // [k][o], padded: layer-1 lanes read distinct banks
  __shared__ float We2T[LDIM][33];
  __shared__ float Wd1T[LDIM][33];
  __shared__ float Wd2T[LDIM][129];  // [k][o], o in 0..127
  __shared__ float ezs[AE_ROWS][P];
  __shared__ float h1s[AE_ROWS][LDIM], zbs[AE_ROWS][LDIM], h2s[AE_ROWS][LDIM];
  __shared__ float be1s[LDIM], be2s[LDIM], bd1s[LDIM], bd2s[P];
  const int tid = threadIdx.x;
  const int r0 = blockIdx.x * AE_ROWS;
  for (int idx = tid; idx < P * LDIM; idx += 256) {
    int o = idx >> 7, k = idx & 127;
    We1T[k][o] = We1[idx];                 // We1 is [L][P] row-major
    int o2 = idx >> 5, k2 = idx & 31;
    Wd2T[k2][o2] = Wd2[idx];               // Wd2 is [P][L] row-major
  }
  for (int idx = tid; idx < LDIM * LDIM; idx += 256) {
    int o = idx >> 5, k = idx & 31;
    We2T[k][o] = We2[idx];
    Wd1T[k][o] = Wd1[idx];
  }
  if (tid < LDIM) { be1s[tid] = be1[tid]; be2s[tid] = be2[tid]; bd1s[tid] = bd1[tid]; }
  if (tid < P) bd2s[tid] = bd2[tid];
  for (int idx = tid; idx < AE_ROWS * P; idx += 256) {
    int r = idx >> 7, c = idx & 127;
    int row = r0 + r;
    float s2 = S2[row];
    float xv = x[(size_t)row * P + c];
    ezs[r][c] = (s2 > 0.0f) ? (ezacc[(size_t)row * P + c] / s2) : xv;
  }
  __syncthreads();
  // Layer 1: 16x32 outputs, dot len 128 -> 2 per thread
  {
    const int o = tid & 31, rh = tid >> 5;
#pragma unroll
    for (int rr = 0; rr < 2; rr++) {
      int r = rh + rr * 8;
      float a = be1s[o];
#pragma unroll 8
      for (int k = 0; k < P; k++) a = fmaf(We1T[k][o], ezs[r][k], a);
      h1s[r][o] = geluf(a);
    }
  }
  __syncthreads();
  // Layer 2: 16x32 outputs, dot len 32
  {
    const int o = tid & 31, rh = tid >> 5;
#pragma unroll
    for (int rr = 0; rr < 2; rr++) {
      int r = rh + rr * 8;
      float a = be2s[o];
#pragma unroll
      for (int k = 0; k < LDIM; k++) a = fmaf(We2T[k][o], h1s[r][k], a);
      zbs[r][o] = a;
    }
  }
  __syncthreads();
  // Layer 3: 16x32 outputs, dot len 32, gelu
  {
    const int o = tid & 31, rh = tid >> 5;
#pragma unroll
    for (int rr = 0; rr < 2; rr++) {
      int r = rh + rr * 8;
      float a = bd1s[o];
#pragma unroll
      for (int k = 0; k < LDIM; k++) a = fmaf(Wd1T[k][o], zbs[r][k], a);
      h2s[r][o] = geluf(a);
    }
  }
  __syncthreads();
  // Layer 4 + sigmoid + MSE: 16x128 outputs, dot len 32 -> 8 per thread
  {
    const int o = tid & 127, rh = tid >> 7;
    float part = 0.0f;
#pragma unroll
    for (int rr = 0; rr < 8; rr++) {
      int r = rh + rr * 2;
      int row = r0 + r;
      float a = bd2s[o];
#pragma unroll
      for (int k = 0; k < LDIM; k++) a = fmaf(Wd2T[k][o], h2s[r][k], a);
      float xh = 1.0f / (1.0f + expf(-a));
      float diff = x[(size_t)row * P + o] - xh;
      part = fmaf(diff, diff, part);
    }
#pragma unroll
    for (int off = 32; off > 0; off >>= 1) part += __shfl_down(part, off);
    if ((tid & 63) == 0) atomicAdd(out, part * (1.0f / ((float)N * (float)P)));
  }
}

extern "C" void kernel_launch(void* const* d_in, const int* in_sizes, int n_in,
                              void* d_out, int out_size, void* d_ws, size_t ws_size,
                              hipStream_t stream) {
  const float* x   = (const float*)d_in[0];
  const float* r0  = (const float*)d_in[1];
  const float* r1  = (const float*)d_in[2];
  const float* r2  = (const float*)d_in[3];
  const float* We1 = (const float*)d_in[4];
  const float* be1 = (const float*)d_in[5];
  const float* We2 = (const float*)d_in[6];
  const float* be2 = (const float*)d_in[7];
  const float* Wd1 = (const float*)d_in[8];
  const float* bd1 = (const float*)d_in[9];
  const float* Wd2 = (const float*)d_in[10];
  const float* bd2 = (const float*)d_in[11];
  float* out = (float*)d_out;

  char* base = (char*)d_ws;
  u16* dist   = (u16*)base;                  // 33554432 B (w1 input for k_wtx<0>)
  u16* betaT  = (u16*)(base + 33554432);     // 33554432 B
  u16* xb     = (u16*)(base + 67108864);     // 1048576 B
  u16* xbT    = (u16*)(base + 68157440);     // 1048576 B
  u16* Ub     = (u16*)(base + 69205888);     // 1048576 B
  float* muacc = (float*)(base + 70254464);  // 2097152 B (recycled as ezacc after k_finU)
  float* x2   = muacc + (size_t)N * P;       // N floats  <- contiguous zero region starts at muacc
  float* S1   = x2 + N;
  float* S2   = S1 + N;
  u32* mdb    = (u32*)(S2 + N);              // 1 (inside zero region)
  float* u2   = (float*)(mdb + 1);           // written fully by k_finU
  float* cj   = u2 + N;
  float* ezacc = muacc;

  const int zcnt = N * P + 3 * N + 1;  // muacc + x2 + S1 + S2 + mdb
  hipLaunchKernelGGL(k_init, dim3((zcnt + 255) / 256), dim3(256), 0, stream, muacc, zcnt, out);
  hipLaunchKernelGGL(k_prep, dim3(N / 32, P / 32), dim3(256), 0, stream, x, xb, xbT, x2);
  hipLaunchKernelGGL(k_dist, dim3(N / 128, N / 128), dim3(256), 0, stream, xb, x2, dist, mdb);
  hipLaunchKernelGGL((k_wtx<0>), dim3(N / 128, 16), dim3(256), 0, stream, dist, xbT, muacc, S1, r0, mdb);
  hipLaunchKernelGGL(k_finU, dim3(N), dim3(128), 0, stream, x, xb, muacc, S1, Ub, u2, cj);
  hipLaunchKernelGGL(k_beta, dim3(N / 128, N / 128), dim3(256), 0, stream, xb, Ub, x2, u2, cj, betaT, r1, r2, mdb);
  hipLaunchKernelGGL((k_wtx<1>), dim3(N / 128, 16), dim3(256), 0, stream, betaT, xbT, ezacc, S2, r0, mdb);
  hipLaunchKernelGGL(k_ae, dim3(N / AE_ROWS), dim3(256), 0, stream, x, ezacc, S2, We1, be1, We2, be2, Wd1, bd1, Wd2, bd2, out);
}

// Round 5
// 253.248 us; speedup vs baseline: 1.4104x; 1.1666x over previous
//
#include <hip/hip_runtime.h>
#include <math.h>

#define N 4096
#define P 128
#define LDIM 32
#define CHUNKS 8
#define ITILES 4

typedef unsigned int u32;
typedef unsigned short u16;
typedef short s16x8 __attribute__((ext_vector_type(8)));
typedef float f32x4 __attribute__((ext_vector_type(4)));

// ---------- bf16 helpers (RNE) ----------
__device__ __forceinline__ u16 f2b(float f) {
  u32 u = __float_as_uint(f);
  u += 0x7fffu + ((u >> 16) & 1u);
  return (u16)(u >> 16);
}
__device__ __forceinline__ float b2f(u16 h) { return __uint_as_float(((u32)h) << 16); }

// ---------- weight functions (match reference) ----------
__device__ __forceinline__ float w2f(float d, float r) {
  if (d < 0.5f * r) return 1.0f;
  if (d < r) { float t = (2.0f * d - r) / r; float b = 1.0f - t * t; return b * b * b; }
  return 0.0f;
}
__device__ __forceinline__ float geluf(float a) {
  return 0.5f * a * (1.0f + erff(a * 0.70710678118654752f));
}

#define MFMA(a, b, c) __builtin_amdgcn_mfma_f32_16x16x32_bf16((a), (b), (c), 0, 0, 0)

// ---------- K0: zero x2+mdb region + out ----------
__global__ __launch_bounds__(256) void k_init(float* __restrict__ z, int cnt, float* __restrict__ out) {
  int i = blockIdx.x * 256 + threadIdx.x;
  if (i < cnt) z[i] = 0.0f;
  if (blockIdx.x == 0 && threadIdx.x == 0) out[0] = 0.0f;
}

// ---------- K1: xb = bf16(x), xbT = transpose, x2 from bf16 values ----------
__global__ __launch_bounds__(256) void k_prep(const float* __restrict__ x, u16* __restrict__ xb,
                                              u16* __restrict__ xbT, float* __restrict__ x2) {
  __shared__ u16 tl[32][36];
  const int bi = blockIdx.x * 32, bk = blockIdx.y * 32;
  const int tid = threadIdx.x;
  const int row = tid >> 3, cs = (tid & 7) * 4;
  float4 v = *(const float4*)&x[(size_t)(bi + row) * P + bk + cs];
  u16 h0 = f2b(v.x), h1 = f2b(v.y), h2 = f2b(v.z), h3 = f2b(v.w);
  float d0 = b2f(h0), d1 = b2f(h1), d2 = b2f(h2), d3 = b2f(h3);
  float s = d0 * d0 + d1 * d1 + d2 * d2 + d3 * d3;
  s += __shfl_down(s, 4); s += __shfl_down(s, 2); s += __shfl_down(s, 1);
  if ((tid & 7) == 0) atomicAdd(&x2[bi + row], s);
  ushort4 o4; o4.x = h0; o4.y = h1; o4.z = h2; o4.w = h3;
  *(ushort4*)(xb + (size_t)(bi + row) * P + bk + cs) = o4;
  tl[row][cs + 0] = h0; tl[row][cs + 1] = h1; tl[row][cs + 2] = h2; tl[row][cs + 3] = h3;
  __syncthreads();
  const int orow = tid >> 3, ocs = (tid & 7) * 4;
  ushort4 t4;
  t4.x = tl[ocs + 0][orow]; t4.y = tl[ocs + 1][orow]; t4.z = tl[ocs + 2][orow]; t4.w = tl[ocs + 3][orow];
  *(ushort4*)(xbT + (size_t)(bk + orow) * N + bi + ocs) = t4;
}

// ---------- K2: max pairwise d2 (no stores). mdb holds bits(max d2). ----------
__global__ __launch_bounds__(256) void k_grammax(const u16* __restrict__ xb, const float* __restrict__ x2,
                                                 u32* __restrict__ mdb) {
  if (blockIdx.y > blockIdx.x) return;  // symmetric
  __shared__ uint4 L[4096];
  const int bi = blockIdx.y * 128, bj = blockIdx.x * 128;
  const int tid = threadIdx.x;
  const int lane = tid & 63, wv = tid >> 6;
  const int wi = wv >> 1, wj = wv & 1;
  const int lm = lane & 15, quad = lane >> 4;
  const uint4* ga = (const uint4*)(xb + (size_t)bi * P);
  const uint4* gb = (const uint4*)(xb + (size_t)bj * P);
#pragma unroll
  for (int it = 0; it < 8; ++it) {
    int c = it * 256 + tid;
    int row = c >> 4, ch = c & 15;
    int sw = row * 16 + (ch ^ (row & 7));
    L[sw] = ga[c];
    L[2048 + sw] = gb[c];
  }
  __syncthreads();
  f32x4 acc[4][4];
#pragma unroll
  for (int u = 0; u < 4; u++)
#pragma unroll
    for (int v = 0; v < 4; v++) acc[u][v] = {0.f, 0.f, 0.f, 0.f};
#pragma unroll
  for (int ks = 0; ks < 4; ++ks) {
    s16x8 af[4], bf[4];
#pragma unroll
    for (int u = 0; u < 4; u++) { int rr = wi * 64 + u * 16 + lm; af[u] = *(const s16x8*)&L[rr * 16 + ((ks * 4 + quad) ^ (rr & 7))]; }
#pragma unroll
    for (int v = 0; v < 4; v++) { int rr = wj * 64 + v * 16 + lm; bf[v] = *(const s16x8*)&L[2048 + rr * 16 + ((ks * 4 + quad) ^ (rr & 7))]; }
#pragma unroll
    for (int u = 0; u < 4; u++)
#pragma unroll
      for (int v = 0; v < 4; v++) acc[u][v] = MFMA(af[u], bf[v], acc[u][v]);
  }
  float lmax = 0.0f;  // clamped >=0 so uint-compare atomicMax is valid
#pragma unroll
  for (int u = 0; u < 4; u++)
#pragma unroll
    for (int v = 0; v < 4; v++) {
      float xjc = x2[bj + wj * 64 + v * 16 + lm];
#pragma unroll
      for (int reg = 0; reg < 4; reg++) {
        float d2 = x2[bi + wi * 64 + u * 16 + quad * 4 + reg] + xjc - 2.0f * acc[u][v][reg];
        lmax = fmaxf(lmax, d2);
      }
    }
#pragma unroll
  for (int o = 32; o > 0; o >>= 1) lmax = fmaxf(lmax, __shfl_down(lmax, o));
  if (lane == 0) atomicMax(mdb, __float_as_uint(lmax));
}

// ---------- K3: fused alpha pass: Gram tile -> w1 -> (LDS transpose) -> PV, partial mu + S1 ----------
__global__ __launch_bounds__(256, 1) void k_alpha(const u16* __restrict__ xb, const u16* __restrict__ xbT,
                                                  const float* __restrict__ x2,
                                                  float* __restrict__ muP, float* __restrict__ S1P,
                                                  const float* __restrict__ r0p, const u32* __restrict__ mdb) {
  __shared__ uint4 LA[2048];   // xb_j rows swizzled (32KB)
  __shared__ uint4 LBW[2304];  // xb_i rows swizzled / W^T overlay stride 136 (36KB)
  __shared__ uint4 LC[2048];   // xbT_i rows swizzled (32KB)
  const int j0 = blockIdx.x * 128;
  const int cid = blockIdx.y;
  const int tid = threadIdx.x;
  const int lane = tid & 63, wv = tid >> 6;
  const int wi = wv >> 1, wj = wv & 1;
  const int lm = lane & 15, quad = lane >> 4;
  u16* W16 = (u16*)LBW;
  {
    const uint4* ga = (const uint4*)(xb + (size_t)j0 * P);
#pragma unroll
    for (int it = 0; it < 8; ++it) {
      int c = it * 256 + tid;
      int row = c >> 4, ch = c & 15;
      LA[row * 16 + (ch ^ (row & 7))] = ga[c];
    }
  }
  const float mdf = sqrtf(fmaxf(__uint_as_float(*mdb), 1e-12f));
  const float re = fminf(r0p[0], mdf);
  const float re2 = re * re;
  const float inv_re2 = 1.0f / re2;
  float x2j[4][4];
#pragma unroll
  for (int u = 0; u < 4; u++)
#pragma unroll
    for (int reg = 0; reg < 4; reg++) x2j[u][reg] = x2[j0 + wi * 64 + u * 16 + quad * 4 + reg];
  f32x4 accPV[4][4];
#pragma unroll
  for (int u = 0; u < 4; u++)
#pragma unroll
    for (int v = 0; v < 4; v++) accPV[u][v] = {0.f, 0.f, 0.f, 0.f};
  float sj = 0.0f;
  const int sj_row = tid >> 1, sj_half = tid & 1;
  for (int t = 0; t < ITILES; ++t) {
    const int i0 = (cid * ITILES + t) * 128;
    __syncthreads();  // A staged (t=0) / prev PV+S1 reads done
    {
      const uint4* gb = (const uint4*)(xb + (size_t)i0 * P);
#pragma unroll
      for (int it = 0; it < 8; ++it) {
        int c = it * 256 + tid;
        int row = c >> 4, ch = c & 15;
        int sw = row * 16 + (ch ^ (row & 7));
        LBW[sw] = gb[c];
        LC[sw] = *(const uint4*)(xbT + (size_t)row * N + i0 + ch * 8);
      }
    }
    __syncthreads();
    f32x4 accG[4][4];
#pragma unroll
    for (int u = 0; u < 4; u++)
#pragma unroll
      for (int v = 0; v < 4; v++) accG[u][v] = {0.f, 0.f, 0.f, 0.f};
#pragma unroll
    for (int ks = 0; ks < 4; ++ks) {
      s16x8 af[4], bf[4];
#pragma unroll
      for (int u = 0; u < 4; u++) { int rr = wi * 64 + u * 16 + lm; af[u] = *(const s16x8*)&LA[rr * 16 + ((ks * 4 + quad) ^ (rr & 7))]; }
#pragma unroll
      for (int v = 0; v < 4; v++) { int rr = wj * 64 + v * 16 + lm; bf[v] = *(const s16x8*)&LBW[rr * 16 + ((ks * 4 + quad) ^ (rr & 7))]; }
#pragma unroll
      for (int u = 0; u < 4; u++)
#pragma unroll
        for (int v = 0; v < 4; v++) accG[u][v] = MFMA(af[u], bf[v], accG[u][v]);
    }
    u16 wvals[4][4][4];
#pragma unroll
    for (int v = 0; v < 4; v++) {
      float x2i = x2[i0 + wj * 64 + v * 16 + lm];
#pragma unroll
      for (int u = 0; u < 4; u++)
#pragma unroll
        for (int reg = 0; reg < 4; reg++) {
          float d2 = fmaxf(x2j[u][reg] + x2i - 2.0f * accG[u][v][reg], 1e-12f);
          float w = 0.0f;
          if (d2 < re2) { float b = 1.0f - d2 * inv_re2; w = b * b * b; }
          wvals[u][v][reg] = f2b(w);
        }
    }
    __syncthreads();  // Gram LDS reads done -> safe to overwrite B region with W
#pragma unroll
    for (int u = 0; u < 4; u++)
#pragma unroll
      for (int v = 0; v < 4; v++) {
        int il = wj * 64 + v * 16 + lm;
#pragma unroll
        for (int reg = 0; reg < 4; reg++) {
          int jl = wi * 64 + u * 16 + quad * 4 + reg;
          W16[jl * 136 + il] = wvals[u][v][reg];
        }
      }
    __syncthreads();
    {  // S1 partial from the exact bf16 values used in the GEMM
      const uint4* wr = (const uint4*)&W16[sj_row * 136 + sj_half * 64];
#pragma unroll
      for (int q = 0; q < 8; ++q) {
        uint4 pk = wr[q];
        u32 a[4] = {pk.x, pk.y, pk.z, pk.w};
#pragma unroll
        for (int e = 0; e < 4; e++) sj += b2f((u16)(a[e] & 0xffffu)) + b2f((u16)(a[e] >> 16));
      }
    }
#pragma unroll
    for (int ks = 0; ks < 4; ++ks) {
      s16x8 aw[4], bx[4];
#pragma unroll
      for (int u = 0; u < 4; u++) { int jr = wi * 64 + u * 16 + lm; aw[u] = *(const s16x8*)&W16[jr * 136 + ks * 32 + quad * 8]; }
#pragma unroll
      for (int v = 0; v < 4; v++) { int rr = wj * 64 + v * 16 + lm; bx[v] = *(const s16x8*)&LC[rr * 16 + ((ks * 4 + quad) ^ (rr & 7))]; }
#pragma unroll
      for (int u = 0; u < 4; u++)
#pragma unroll
        for (int v = 0; v < 4; v++) accPV[u][v] = MFMA(aw[u], bx[v], accPV[u][v]);
    }
  }
  float* mu = muP + (size_t)cid * N * P;
#pragma unroll
  for (int u = 0; u < 4; u++)
#pragma unroll
    for (int v = 0; v < 4; v++) {
      int pc = wj * 64 + v * 16 + lm;
#pragma unroll
      for (int reg = 0; reg < 4; reg++) {
        int jl = wi * 64 + u * 16 + quad * 4 + reg;
        mu[(size_t)(j0 + jl) * P + pc] = accPV[u][v][reg];
      }
    }
  sj += __shfl_down(sj, 1);
  if (sj_half == 0) S1P[cid * N + j0 + sj_row] = sj;
}

// ---------- K4: U finalize (reduce muP partials), Ub=bf16(U), u2,cj from bf16 ----------
__global__ __launch_bounds__(128) void k_finU(const float* __restrict__ x, const u16* __restrict__ xb,
                                              const float* __restrict__ muP, const float* __restrict__ S1P,
                                              u16* __restrict__ Ub, float* __restrict__ u2, float* __restrict__ cj) {
  const int j = blockIdx.x, t = threadIdx.x;
  float ssum = 0.0f, msum = 0.0f;
#pragma unroll
  for (int c = 0; c < CHUNKS; ++c) {
    ssum += S1P[c * N + j];
    msum += muP[((size_t)c * N + j) * P + t];
  }
  float xv = x[(size_t)j * P + t];
  float uval = 0.0f;
  if (ssum > 0.0f) uval = xv - msum / ssum;
  u16 ub = f2b(uval);
  Ub[(size_t)j * P + t] = ub;
  float uf = b2f(ub);
  float xbf = b2f(xb[(size_t)j * P + t]);
  float a = uf * uf, b = xbf * uf;
#pragma unroll
  for (int o = 32; o > 0; o >>= 1) { a += __shfl_down(a, o); b += __shfl_down(b, o); }
  __shared__ float ra[2], rb[2];
  if ((t & 63) == 0) { ra[t >> 6] = a; rb[t >> 6] = b; }
  __syncthreads();
  if (t == 0) { u2[j] = ra[0] + ra[1]; cj[j] = rb[0] + rb[1]; }
}

// ---------- K5: fused beta pass: two Grams -> w2 -> (LDS transpose) -> PV, partial ez + S2 ----------
__global__ __launch_bounds__(256, 1) void k_betaez(const u16* __restrict__ xb, const u16* __restrict__ Ub,
                                                   const u16* __restrict__ xbT,
                                                   const float* __restrict__ x2, const float* __restrict__ u2,
                                                   const float* __restrict__ cj,
                                                   float* __restrict__ ezP, float* __restrict__ S2P,
                                                   const float* __restrict__ r1p, const float* __restrict__ r2p,
                                                   const u32* __restrict__ mdb) {
  __shared__ uint4 LA[2048];   // xb_j rows swizzled
  __shared__ uint4 LU[2048];   // Ub_j rows swizzled
  __shared__ uint4 LBW[2304];  // xb_i rows swizzled / W^T overlay stride 136
  __shared__ uint4 LC[2048];   // xbT_i rows swizzled
  const int j0 = blockIdx.x * 128;
  const int cid = blockIdx.y;
  const int tid = threadIdx.x;
  const int lane = tid & 63, wv = tid >> 6;
  const int wi = wv >> 1, wj = wv & 1;
  const int lm = lane & 15, quad = lane >> 4;
  u16* W16 = (u16*)LBW;
  {
    const uint4* ga = (const uint4*)(xb + (size_t)j0 * P);
    const uint4* gu = (const uint4*)(Ub + (size_t)j0 * P);
#pragma unroll
    for (int it = 0; it < 8; ++it) {
      int c = it * 256 + tid;
      int row = c >> 4, ch = c & 15;
      int sw = row * 16 + (ch ^ (row & 7));
      LA[sw] = ga[c];
      LU[sw] = gu[c];
    }
  }
  const float mdf = sqrtf(fmaxf(__uint_as_float(*mdb), 1e-12f));
  const float r1e = fminf(r1p[0], mdf), r2e = fminf(r2p[0], mdf);
  float x2j[4][4], u2j[4][4], cjj[4][4];
#pragma unroll
  for (int u = 0; u < 4; u++)
#pragma unroll
    for (int reg = 0; reg < 4; reg++) {
      int j = j0 + wi * 64 + u * 16 + quad * 4 + reg;
      x2j[u][reg] = x2[j]; u2j[u][reg] = u2[j]; cjj[u][reg] = cj[j];
    }
  f32x4 accPV[4][4];
#pragma unroll
  for (int u = 0; u < 4; u++)
#pragma unroll
    for (int v = 0; v < 4; v++) accPV[u][v] = {0.f, 0.f, 0.f, 0.f};
  float sj = 0.0f;
  const int sj_row = tid >> 1, sj_half = tid & 1;
  for (int t = 0; t < ITILES; ++t) {
    const int i0 = (cid * ITILES + t) * 128;
    __syncthreads();
    {
      const uint4* gb = (const uint4*)(xb + (size_t)i0 * P);
#pragma unroll
      for (int it = 0; it < 8; ++it) {
        int c = it * 256 + tid;
        int row = c >> 4, ch = c & 15;
        int sw = row * 16 + (ch ^ (row & 7));
        LBW[sw] = gb[c];
        LC[sw] = *(const uint4*)(xbT + (size_t)row * N + i0 + ch * 8);
      }
    }
    __syncthreads();
    f32x4 accG[4][4], accP[4][4];
#pragma unroll
    for (int u = 0; u < 4; u++)
#pragma unroll
      for (int v = 0; v < 4; v++) { accG[u][v] = {0.f, 0.f, 0.f, 0.f}; accP[u][v] = {0.f, 0.f, 0.f, 0.f}; }
#pragma unroll
    for (int ks = 0; ks < 4; ++ks) {
      s16x8 af[4], au[4], bf[4];
#pragma unroll
      for (int u = 0; u < 4; u++) {
        int rr = wi * 64 + u * 16 + lm;
        int off = rr * 16 + ((ks * 4 + quad) ^ (rr & 7));
        af[u] = *(const s16x8*)&LA[off];
        au[u] = *(const s16x8*)&LU[off];
      }
#pragma unroll
      for (int v = 0; v < 4; v++) { int rr = wj * 64 + v * 16 + lm; bf[v] = *(const s16x8*)&LBW[rr * 16 + ((ks * 4 + quad) ^ (rr & 7))]; }
#pragma unroll
      for (int u = 0; u < 4; u++)
#pragma unroll
        for (int v = 0; v < 4; v++) {
          accG[u][v] = MFMA(af[u], bf[v], accG[u][v]);
          accP[u][v] = MFMA(au[u], bf[v], accP[u][v]);
        }
    }
    u16 wvals[4][4][4];
#pragma unroll
    for (int v = 0; v < 4; v++) {
      float x2i = x2[i0 + wj * 64 + v * 16 + lm];
#pragma unroll
      for (int u = 0; u < 4; u++)
#pragma unroll
        for (int reg = 0; reg < 4; reg++) {
          float d2 = fmaxf(x2j[u][reg] + x2i - 2.0f * accG[u][v][reg], 1e-12f);
          float ps = accP[u][v][reg] - cjj[u][reg];
          float du2 = fmaxf(ps * ps * u2j[u][reg], 1e-6f);
          float dv = sqrtf(fmaxf(d2 - du2, 1e-6f));
          float du = sqrtf(du2);
          wvals[u][v][reg] = f2b(w2f(dv, r1e) * w2f(du, r2e));
        }
    }
    __syncthreads();
#pragma unroll
    for (int u = 0; u < 4; u++)
#pragma unroll
      for (int v = 0; v < 4; v++) {
        int il = wj * 64 + v * 16 + lm;
#pragma unroll
        for (int reg = 0; reg < 4; reg++) {
          int jl = wi * 64 + u * 16 + quad * 4 + reg;
          W16[jl * 136 + il] = wvals[u][v][reg];
        }
      }
    __syncthreads();
    {
      const uint4* wr = (const uint4*)&W16[sj_row * 136 + sj_half * 64];
#pragma unroll
      for (int q = 0; q < 8; ++q) {
        uint4 pk = wr[q];
        u32 a[4] = {pk.x, pk.y, pk.z, pk.w};
#pragma unroll
        for (int e = 0; e < 4; e++) sj += b2f((u16)(a[e] & 0xffffu)) + b2f((u16)(a[e] >> 16));
      }
    }
#pragma unroll
    for (int ks = 0; ks < 4; ++ks) {
      s16x8 aw[4], bx[4];
#pragma unroll
      for (int u = 0; u < 4; u++) { int jr = wi * 64 + u * 16 + lm; aw[u] = *(const s16x8*)&W16[jr * 136 + ks * 32 + quad * 8]; }
#pragma unroll
      for (int v = 0; v < 4; v++) { int rr = wj * 64 + v * 16 + lm; bx[v] = *(const s16x8*)&LC[rr * 16 + ((ks * 4 + quad) ^ (rr & 7))]; }
#pragma unroll
      for (int u = 0; u < 4; u++)
#pragma unroll
        for (int v = 0; v < 4; v++) accPV[u][v] = MFMA(aw[u], bx[v], accPV[u][v]);
    }
  }
  float* ez = ezP + (size_t)cid * N * P;
#pragma unroll
  for (int u = 0; u < 4; u++)
#pragma unroll
    for (int v = 0; v < 4; v++) {
      int pc = wj * 64 + v * 16 + lm;
#pragma unroll
      for (int reg = 0; reg < 4; reg++) {
        int jl = wi * 64 + u * 16 + quad * 4 + reg;
        ez[(size_t)(j0 + jl) * P + pc] = accPV[u][v][reg];
      }
    }
  sj += __shfl_down(sj, 1);
  if (sj_half == 0) S2P[cid * N + j0 + sj_row] = sj;
}

// ---------- K6: e_Z reduce+normalize + autoencoder + MSE (16 rows/block, weights in LDS) ----------
#define AE_ROWS 16
__global__ __launch_bounds__(256) void k_ae(const float* __restrict__ x, const float* __restrict__ ezP,
                                            const float* __restrict__ S2P,
                                            const float* __restrict__ We1, const float* __restrict__ be1,
                                            const float* __restrict__ We2, const float* __restrict__ be2,
                                            const float* __restrict__ Wd1, const float* __restrict__ bd1,
                                            const float* __restrict__ Wd2, const float* __restrict__ bd2,
                                            float* __restrict__ out) {
  __shared__ float We1T[P][33];
  __shared__ float We2T[LDIM][33];
  __shared__ float Wd1T[LDIM][33];
  __shared__ float Wd2T[LDIM][129];
  __shared__ float ezs[AE_ROWS][P];
  __shared__ float h1s[AE_ROWS][LDIM], zbs[AE_ROWS][LDIM], h2s[AE_ROWS][LDIM];
  __shared__ float be1s[LDIM], be2s[LDIM], bd1s[LDIM], bd2s[P];
  __shared__ float s2s[AE_ROWS];
  const int tid = threadIdx.x;
  const int r0 = blockIdx.x * AE_ROWS;
  for (int idx = tid; idx < P * LDIM; idx += 256) {
    int o = idx >> 7, k = idx & 127;
    We1T[k][o] = We1[idx];
    int o2 = idx >> 5, k2 = idx & 31;
    Wd2T[k2][o2] = Wd2[idx];
  }
  for (int idx = tid; idx < LDIM * LDIM; idx += 256) {
    int o = idx >> 5, k = idx & 31;
    We2T[k][o] = We2[idx];
    Wd1T[k][o] = Wd1[idx];
  }
  if (tid < LDIM) { be1s[tid] = be1[tid]; be2s[tid] = be2[tid]; bd1s[tid] = bd1[tid]; }
  if (tid < P) bd2s[tid] = bd2[tid];
  if (tid < AE_ROWS) {
    float s = 0.0f;
#pragma unroll
    for (int c = 0; c < CHUNKS; ++c) s += S2P[c * N + r0 + tid];
    s2s[tid] = s;
  }
  __syncthreads();
  for (int idx = tid; idx < AE_ROWS * P; idx += 256) {
    int r = idx >> 7, col = idx & 127;
    int row = r0 + r;
    float es = 0.0f;
#pragma unroll
    for (int c = 0; c < CHUNKS; ++c) es += ezP[((size_t)c * N + row) * P + col];
    float xv = x[(size_t)row * P + col];
    ezs[r][col] = (s2s[r] > 0.0f) ? (es / s2s[r]) : xv;
  }
  __syncthreads();
  {
    const int o = tid & 31, rh = tid >> 5;
#pragma unroll
    for (int rr = 0; rr < 2; rr++) {
      int r = rh + rr * 8;
      float a = be1s[o];
#pragma unroll 8
      for (int k = 0; k < P; k++) a = fmaf(We1T[k][o], ezs[r][k], a);
      h1s[r][o] = geluf(a);
    }
  }
  __syncthreads();
  {
    const int o = tid & 31, rh = tid >> 5;
#pragma unroll
    for (int rr = 0; rr < 2; rr++) {
      int r = rh + rr * 8;
      float a = be2s[o];
#pragma unroll
      for (int k = 0; k < LDIM; k++) a = fmaf(We2T[k][o], h1s[r][k], a);
      zbs[r][o] = a;
    }
  }
  __syncthreads();
  {
    const int o = tid & 31, rh = tid >> 5;
#pragma unroll
    for (int rr = 0; rr < 2; rr++) {
      int r = rh + rr * 8;
      float a = bd1s[o];
#pragma unroll
      for (int k = 0; k < LDIM; k++) a = fmaf(Wd1T[k][o], zbs[r][k], a);
      h2s[r][o] = geluf(a);
    }
  }
  __syncthreads();
  {
    const int o = tid & 127, rh = tid >> 7;
    float part = 0.0f;
#pragma unroll
    for (int rr = 0; rr < 8; rr++) {
      int r = rh + rr * 2;
      int row = r0 + r;
      float a = bd2s[o];
#pragma unroll
      for (int k = 0; k < LDIM; k++) a = fmaf(Wd2T[k][o], h2s[r][k], a);
      float xh = 1.0f / (1.0f + expf(-a));
      float diff = x[(size_t)row * P + o] - xh;
      part = fmaf(diff, diff, part);
    }
#pragma unroll
    for (int off = 32; off > 0; off >>= 1) part += __shfl_down(part, off);
    if ((tid & 63) == 0) atomicAdd(out, part * (1.0f / ((float)N * (float)P)));
  }
}

extern "C" void kernel_launch(void* const* d_in, const int* in_sizes, int n_in,
                              void* d_out, int out_size, void* d_ws, size_t ws_size,
                              hipStream_t stream) {
  const float* x   = (const float*)d_in[0];
  const float* r0  = (const float*)d_in[1];
  const float* r1  = (const float*)d_in[2];
  const float* r2  = (const float*)d_in[3];
  const float* We1 = (const float*)d_in[4];
  const float* be1 = (const float*)d_in[5];
  const float* We2 = (const float*)d_in[6];
  const float* be2 = (const float*)d_in[7];
  const float* Wd1 = (const float*)d_in[8];
  const float* bd1 = (const float*)d_in[9];
  const float* Wd2 = (const float*)d_in[10];
  const float* bd2 = (const float*)d_in[11];
  float* out = (float*)d_out;

  char* base = (char*)d_ws;
  size_t off = 0;
  u16* xb  = (u16*)(base + off); off += (size_t)N * P * 2;            // 1MB
  u16* xbT = (u16*)(base + off); off += (size_t)N * P * 2;            // 1MB
  u16* Ub  = (u16*)(base + off); off += (size_t)N * P * 2;            // 1MB
  float* muP = (float*)(base + off); off += (size_t)CHUNKS * N * P * 4;  // 16MB
  float* ezP = (float*)(base + off); off += (size_t)CHUNKS * N * P * 4;  // 16MB
  float* S1P = (float*)(base + off); off += (size_t)CHUNKS * N * 4;
  float* S2P = (float*)(base + off); off += (size_t)CHUNKS * N * 4;
  float* x2  = (float*)(base + off); off += (size_t)N * 4;
  u32* mdb   = (u32*)(base + off); off += 4;                          // contiguous after x2 (zeroed together)
  float* u2  = (float*)(base + off); off += (size_t)N * 4;
  float* cjv = (float*)(base + off); off += (size_t)N * 4;

  const int zcnt = N + 1;  // x2 + mdb
  hipLaunchKernelGGL(k_init, dim3((zcnt + 255) / 256), dim3(256), 0, stream, x2, zcnt, out);
  hipLaunchKernelGGL(k_prep, dim3(N / 32, P / 32), dim3(256), 0, stream, x, xb, xbT, x2);
  hipLaunchKernelGGL(k_grammax, dim3(N / 128, N / 128), dim3(256), 0, stream, xb, x2, mdb);
  hipLaunchKernelGGL(k_alpha, dim3(N / 128, CHUNKS), dim3(256), 0, stream, xb, xbT, x2, muP, S1P, r0, mdb);
  hipLaunchKernelGGL(k_finU, dim3(N), dim3(128), 0, stream, x, xb, muP, S1P, Ub, u2, cjv);
  hipLaunchKernelGGL(k_betaez, dim3(N / 128, CHUNKS), dim3(256), 0, stream, xb, Ub, xbT, x2, u2, cjv, ezP, S2P, r1, r2, mdb);
  hipLaunchKernelGGL(k_ae, dim3(N / AE_ROWS), dim3(256), 0, stream, x, ezP, S2P, We1, be1, We2, be2, Wd1, bd1, Wd2, bd2, out);
}

// Round 6
// 201.019 us; speedup vs baseline: 1.7768x; 1.2598x over previous
//
#include <hip/hip_runtime.h>
#include <math.h>

#define N 4096
#define P 128
#define LDIM 32
#define CHUNKS 8
#define ITILES 4

typedef unsigned int u32;
typedef unsigned short u16;
typedef short s16x8 __attribute__((ext_vector_type(8)));
typedef float f32x4 __attribute__((ext_vector_type(4)));

// ---------- bf16 helpers (RNE) ----------
__device__ __forceinline__ u16 f2b(float f) {
  u32 u = __float_as_uint(f);
  u += 0x7fffu + ((u >> 16) & 1u);
  return (u16)(u >> 16);
}
__device__ __forceinline__ float b2f(u16 h) { return __uint_as_float(((u32)h) << 16); }

// ---------- weight functions (match reference) ----------
__device__ __forceinline__ float w2f(float d, float r) {
  if (d < 0.5f * r) return 1.0f;
  if (d < r) { float t = (2.0f * d - r) / r; float b = 1.0f - t * t; return b * b * b; }
  return 0.0f;
}
__device__ __forceinline__ float geluf(float a) {
  return 0.5f * a * (1.0f + erff(a * 0.70710678118654752f));
}

#define MFMA(a, b, c) __builtin_amdgcn_mfma_f32_16x16x32_bf16((a), (b), (c), 0, 0, 0)

// ---------- K0: zero x2+mdb region + out ----------
__global__ __launch_bounds__(256) void k_init(float* __restrict__ z, int cnt, float* __restrict__ out) {
  int i = blockIdx.x * 256 + threadIdx.x;
  if (i < cnt) z[i] = 0.0f;
  if (blockIdx.x == 0 && threadIdx.x == 0) out[0] = 0.0f;
}

// ---------- K1: xb = bf16(x), xbT = transpose, x2 from bf16 values ----------
__global__ __launch_bounds__(256) void k_prep(const float* __restrict__ x, u16* __restrict__ xb,
                                              u16* __restrict__ xbT, float* __restrict__ x2) {
  __shared__ u16 tl[32][36];
  const int bi = blockIdx.x * 32, bk = blockIdx.y * 32;
  const int tid = threadIdx.x;
  const int row = tid >> 3, cs = (tid & 7) * 4;
  float4 v = *(const float4*)&x[(size_t)(bi + row) * P + bk + cs];
  u16 h0 = f2b(v.x), h1 = f2b(v.y), h2 = f2b(v.z), h3 = f2b(v.w);
  float d0 = b2f(h0), d1 = b2f(h1), d2 = b2f(h2), d3 = b2f(h3);
  float s = d0 * d0 + d1 * d1 + d2 * d2 + d3 * d3;
  s += __shfl_down(s, 4); s += __shfl_down(s, 2); s += __shfl_down(s, 1);
  if ((tid & 7) == 0) atomicAdd(&x2[bi + row], s);
  ushort4 o4; o4.x = h0; o4.y = h1; o4.z = h2; o4.w = h3;
  *(ushort4*)(xb + (size_t)(bi + row) * P + bk + cs) = o4;
  tl[row][cs + 0] = h0; tl[row][cs + 1] = h1; tl[row][cs + 2] = h2; tl[row][cs + 3] = h3;
  __syncthreads();
  const int orow = tid >> 3, ocs = (tid & 7) * 4;
  ushort4 t4;
  t4.x = tl[ocs + 0][orow]; t4.y = tl[ocs + 1][orow]; t4.z = tl[ocs + 2][orow]; t4.w = tl[ocs + 3][orow];
  *(ushort4*)(xbT + (size_t)(bk + orow) * N + bi + ocs) = t4;
}

// ---------- K2: max pairwise d2 (no stores). mdb holds bits(max d2). ----------
// 64-row j-tile in LDS; i-side read direct from global. 512 threads = 8 waves, each wave a 16-wide i-slice.
__global__ __launch_bounds__(512, 4) void k_grammax(const u16* __restrict__ xb, const float* __restrict__ x2,
                                                    u32* __restrict__ mdb) {
  __shared__ uint4 LA[1024];
  const int j0 = blockIdx.x * 64;
  const int cid = blockIdx.y;
  if (cid * 512 + 512 <= j0) return;  // upper triangle only (uniform)
  const int tid = threadIdx.x;
  const int lane = tid & 63, w = tid >> 6;
  const int lm = lane & 15, quad = lane >> 4;
  {
    const uint4* g = (const uint4*)(xb + (size_t)j0 * P);
#pragma unroll
    for (int it = 0; it < 2; ++it) {
      int c = it * 512 + tid;
      int row = c >> 4, ch = c & 15;
      LA[row * 16 + (ch ^ (row & 7))] = g[c];
    }
  }
  float x2j[4][4];
#pragma unroll
  for (int u = 0; u < 4; u++)
#pragma unroll
    for (int reg = 0; reg < 4; reg++) x2j[u][reg] = x2[j0 + u * 16 + quad * 4 + reg];
  __syncthreads();
  float lmax = 0.0f;
  for (int t = 0; t < ITILES; ++t) {
    const int i0 = cid * 512 + t * 128;
    if (i0 + 128 <= j0) continue;  // uniform, no barriers in loop
    f32x4 accG[4];
#pragma unroll
    for (int u = 0; u < 4; u++) accG[u] = {0.f, 0.f, 0.f, 0.f};
    const u16* gb = xb + (size_t)(i0 + w * 16 + lm) * P;
#pragma unroll
    for (int ks = 0; ks < 4; ++ks) {
      s16x8 bf = *(const s16x8*)(gb + ks * 32 + quad * 8);
      s16x8 af[4];
#pragma unroll
      for (int u = 0; u < 4; u++) { int m = u * 16 + lm; af[u] = *(const s16x8*)&LA[m * 16 + ((ks * 4 + quad) ^ (m & 7))]; }
#pragma unroll
      for (int u = 0; u < 4; u++) accG[u] = MFMA(af[u], bf, accG[u]);
    }
    float x2i = x2[i0 + w * 16 + lm];
#pragma unroll
    for (int u = 0; u < 4; u++)
#pragma unroll
      for (int reg = 0; reg < 4; reg++) lmax = fmaxf(lmax, x2j[u][reg] + x2i - 2.0f * accG[u][reg]);
  }
#pragma unroll
  for (int o = 32; o > 0; o >>= 1) lmax = fmaxf(lmax, __shfl_down(lmax, o));
  if (lane == 0) atomicMax(mdb, __float_as_uint(lmax));
}

// ---------- K3: fused alpha: Gram -> w1 -> W(LDS) -> PV, partial mu + S1. 64-j tile, 512 thr ----------
__global__ __launch_bounds__(512, 4) void k_alpha(const u16* __restrict__ xb, const u16* __restrict__ xbT,
                                                  const float* __restrict__ x2,
                                                  float* __restrict__ muP, float* __restrict__ S1P,
                                                  const float* __restrict__ r0p, const u32* __restrict__ mdb) {
  __shared__ uint4 LA[1024];     // xb_j 64x128 swizzled (16KB)
  __shared__ u16 W16[64 * 136];  // weight tile, A-layout rows j (17KB)
  const int j0 = blockIdx.x * 64, cid = blockIdx.y;
  const int tid = threadIdx.x;
  const int lane = tid & 63, w = tid >> 6;
  const int lm = lane & 15, quad = lane >> 4;
  {
    const uint4* g = (const uint4*)(xb + (size_t)j0 * P);
#pragma unroll
    for (int it = 0; it < 2; ++it) {
      int c = it * 512 + tid;
      int row = c >> 4, ch = c & 15;
      LA[row * 16 + (ch ^ (row & 7))] = g[c];
    }
  }
  const float mdf = sqrtf(fmaxf(__uint_as_float(*mdb), 1e-12f));
  const float re = fminf(r0p[0], mdf);
  const float re2 = re * re, inv_re2 = 1.0f / re2;
  float x2j[4][4];
#pragma unroll
  for (int u = 0; u < 4; u++)
#pragma unroll
    for (int reg = 0; reg < 4; reg++) x2j[u][reg] = x2[j0 + u * 16 + quad * 4 + reg];
  f32x4 accPV[4];
#pragma unroll
  for (int u = 0; u < 4; u++) accPV[u] = {0.f, 0.f, 0.f, 0.f};
  float sjacc = 0.0f;
  const int srow = tid >> 3, spart = tid & 7;
  __syncthreads();
  for (int t = 0; t < ITILES; ++t) {
    const int i0 = cid * 512 + t * 128;
    f32x4 accG[4];
#pragma unroll
    for (int u = 0; u < 4; u++) accG[u] = {0.f, 0.f, 0.f, 0.f};
    const u16* gb = xb + (size_t)(i0 + w * 16 + lm) * P;
#pragma unroll
    for (int ks = 0; ks < 4; ++ks) {
      s16x8 bf = *(const s16x8*)(gb + ks * 32 + quad * 8);
      s16x8 af[4];
#pragma unroll
      for (int u = 0; u < 4; u++) { int m = u * 16 + lm; af[u] = *(const s16x8*)&LA[m * 16 + ((ks * 4 + quad) ^ (m & 7))]; }
#pragma unroll
      for (int u = 0; u < 4; u++) accG[u] = MFMA(af[u], bf, accG[u]);
    }
    float x2i = x2[i0 + w * 16 + lm];
    u16 wv[4][4];
#pragma unroll
    for (int u = 0; u < 4; u++)
#pragma unroll
      for (int reg = 0; reg < 4; reg++) {
        float d2 = fmaxf(x2j[u][reg] + x2i - 2.0f * accG[u][reg], 1e-12f);
        float wt = 0.0f;
        if (d2 < re2) { float b = 1.0f - d2 * inv_re2; wt = b * b * b; }
        wv[u][reg] = f2b(wt);
      }
    __syncthreads();  // prev tile's W16 readers (Sj + PV) done
#pragma unroll
    for (int u = 0; u < 4; u++)
#pragma unroll
      for (int reg = 0; reg < 4; reg++)
        W16[(u * 16 + quad * 4 + reg) * 136 + w * 16 + lm] = wv[u][reg];
    __syncthreads();
    {  // S1 partial from exact bf16 W values
      const uint4* wr = (const uint4*)&W16[srow * 136 + spart * 16];
      uint4 a0 = wr[0], a1 = wr[1];
      u32 arr[8] = {a0.x, a0.y, a0.z, a0.w, a1.x, a1.y, a1.z, a1.w};
#pragma unroll
      for (int e = 0; e < 8; e++) sjacc += b2f((u16)(arr[e] & 0xffffu)) + b2f((u16)(arr[e] >> 16));
    }
    const u16* gx = xbT + (size_t)(w * 16 + lm) * N + i0;
#pragma unroll
    for (int ks = 0; ks < 4; ++ks) {
      s16x8 bx = *(const s16x8*)(gx + ks * 32 + quad * 8);
      s16x8 aw[4];
#pragma unroll
      for (int u = 0; u < 4; u++) { int m = u * 16 + lm; aw[u] = *(const s16x8*)&W16[m * 136 + ks * 32 + quad * 8]; }
#pragma unroll
      for (int u = 0; u < 4; u++) accPV[u] = MFMA(aw[u], bx, accPV[u]);
    }
  }
  float* mu = muP + (size_t)cid * N * P;
#pragma unroll
  for (int u = 0; u < 4; u++)
#pragma unroll
    for (int reg = 0; reg < 4; reg++)
      mu[(size_t)(j0 + u * 16 + quad * 4 + reg) * P + w * 16 + lm] = accPV[u][reg];
  sjacc += __shfl_down(sjacc, 4);
  sjacc += __shfl_down(sjacc, 2);
  sjacc += __shfl_down(sjacc, 1);
  if (spart == 0) S1P[cid * N + j0 + srow] = sjacc;
}

// ---------- K4: U finalize (reduce muP partials), Ub=bf16(U), u2,cj from bf16 ----------
__global__ __launch_bounds__(128) void k_finU(const float* __restrict__ x, const u16* __restrict__ xb,
                                              const float* __restrict__ muP, const float* __restrict__ S1P,
                                              u16* __restrict__ Ub, float* __restrict__ u2, float* __restrict__ cj) {
  const int j = blockIdx.x, t = threadIdx.x;
  float ssum = 0.0f, msum = 0.0f;
#pragma unroll
  for (int c = 0; c < CHUNKS; ++c) {
    ssum += S1P[c * N + j];
    msum += muP[((size_t)c * N + j) * P + t];
  }
  float xv = x[(size_t)j * P + t];
  float uval = 0.0f;
  if (ssum > 0.0f) uval = xv - msum / ssum;
  u16 ub = f2b(uval);
  Ub[(size_t)j * P + t] = ub;
  float uf = b2f(ub);
  float xbf = b2f(xb[(size_t)j * P + t]);
  float a = uf * uf, b = xbf * uf;
#pragma unroll
  for (int o = 32; o > 0; o >>= 1) { a += __shfl_down(a, o); b += __shfl_down(b, o); }
  __shared__ float ra[2], rb[2];
  if ((t & 63) == 0) { ra[t >> 6] = a; rb[t >> 6] = b; }
  __syncthreads();
  if (t == 0) { u2[j] = ra[0] + ra[1]; cj[j] = rb[0] + rb[1]; }
}

// ---------- K5: fused beta: two Grams -> w2 -> W(LDS) -> PV, partial ez + S2. 64-j tile, 512 thr ----------
__global__ __launch_bounds__(512, 4) void k_betaez(const u16* __restrict__ xb, const u16* __restrict__ Ub,
                                                   const u16* __restrict__ xbT,
                                                   const float* __restrict__ x2, const float* __restrict__ u2,
                                                   const float* __restrict__ cj,
                                                   float* __restrict__ ezP, float* __restrict__ S2P,
                                                   const float* __restrict__ r1p, const float* __restrict__ r2p,
                                                   const u32* __restrict__ mdb) {
  __shared__ uint4 LA[1024];     // xb_j swizzled
  __shared__ uint4 LU[1024];     // Ub_j swizzled
  __shared__ u16 W16[64 * 136];
  __shared__ float SX2[64], SU2[64], SCJ[64];
  const int j0 = blockIdx.x * 64, cid = blockIdx.y;
  const int tid = threadIdx.x;
  const int lane = tid & 63, w = tid >> 6;
  const int lm = lane & 15, quad = lane >> 4;
  {
    const uint4* ga = (const uint4*)(xb + (size_t)j0 * P);
    const uint4* gu = (const uint4*)(Ub + (size_t)j0 * P);
#pragma unroll
    for (int it = 0; it < 2; ++it) {
      int c = it * 512 + tid;
      int row = c >> 4, ch = c & 15;
      int sw = row * 16 + (ch ^ (row & 7));
      LA[sw] = ga[c];
      LU[sw] = gu[c];
    }
  }
  if (tid < 64) { SX2[tid] = x2[j0 + tid]; SU2[tid] = u2[j0 + tid]; SCJ[tid] = cj[j0 + tid]; }
  const float mdf = sqrtf(fmaxf(__uint_as_float(*mdb), 1e-12f));
  const float r1e = fminf(r1p[0], mdf), r2e = fminf(r2p[0], mdf);
  f32x4 accPV[4];
#pragma unroll
  for (int u = 0; u < 4; u++) accPV[u] = {0.f, 0.f, 0.f, 0.f};
  float sjacc = 0.0f;
  const int srow = tid >> 3, spart = tid & 7;
  __syncthreads();
  for (int t = 0; t < ITILES; ++t) {
    const int i0 = cid * 512 + t * 128;
    f32x4 accG[4], accP[4];
#pragma unroll
    for (int u = 0; u < 4; u++) { accG[u] = {0.f, 0.f, 0.f, 0.f}; accP[u] = {0.f, 0.f, 0.f, 0.f}; }
    const u16* gb = xb + (size_t)(i0 + w * 16 + lm) * P;
#pragma unroll
    for (int ks = 0; ks < 4; ++ks) {
      s16x8 bf = *(const s16x8*)(gb + ks * 32 + quad * 8);
      s16x8 af[4], au[4];
#pragma unroll
      for (int u = 0; u < 4; u++) {
        int m = u * 16 + lm;
        int off = m * 16 + ((ks * 4 + quad) ^ (m & 7));
        af[u] = *(const s16x8*)&LA[off];
        au[u] = *(const s16x8*)&LU[off];
      }
#pragma unroll
      for (int u = 0; u < 4; u++) {
        accG[u] = MFMA(af[u], bf, accG[u]);
        accP[u] = MFMA(au[u], bf, accP[u]);
      }
    }
    float x2i = x2[i0 + w * 16 + lm];
    u16 wv[4][4];
#pragma unroll
    for (int u = 0; u < 4; u++)
#pragma unroll
      for (int reg = 0; reg < 4; reg++) {
        int jj = u * 16 + quad * 4 + reg;
        float d2 = fmaxf(SX2[jj] + x2i - 2.0f * accG[u][reg], 1e-12f);
        float ps = accP[u][reg] - SCJ[jj];
        float du2 = fmaxf(ps * ps * SU2[jj], 1e-6f);
        float dv = sqrtf(fmaxf(d2 - du2, 1e-6f));
        float du = sqrtf(du2);
        wv[u][reg] = f2b(w2f(dv, r1e) * w2f(du, r2e));
      }
    __syncthreads();
#pragma unroll
    for (int u = 0; u < 4; u++)
#pragma unroll
      for (int reg = 0; reg < 4; reg++)
        W16[(u * 16 + quad * 4 + reg) * 136 + w * 16 + lm] = wv[u][reg];
    __syncthreads();
    {
      const uint4* wr = (const uint4*)&W16[srow * 136 + spart * 16];
      uint4 a0 = wr[0], a1 = wr[1];
      u32 arr[8] = {a0.x, a0.y, a0.z, a0.w, a1.x, a1.y, a1.z, a1.w};
#pragma unroll
      for (int e = 0; e < 8; e++) sjacc += b2f((u16)(arr[e] & 0xffffu)) + b2f((u16)(arr[e] >> 16));
    }
    const u16* gx = xbT + (size_t)(w * 16 + lm) * N + i0;
#pragma unroll
    for (int ks = 0; ks < 4; ++ks) {
      s16x8 bx = *(const s16x8*)(gx + ks * 32 + quad * 8);
      s16x8 aw[4];
#pragma unroll
      for (int u = 0; u < 4; u++) { int m = u * 16 + lm; aw[u] = *(const s16x8*)&W16[m * 136 + ks * 32 + quad * 8]; }
#pragma unroll
      for (int u = 0; u < 4; u++) accPV[u] = MFMA(aw[u], bx, accPV[u]);
    }
  }
  float* ez = ezP + (size_t)cid * N * P;
#pragma unroll
  for (int u = 0; u < 4; u++)
#pragma unroll
    for (int reg = 0; reg < 4; reg++)
      ez[(size_t)(j0 + u * 16 + quad * 4 + reg) * P + w * 16 + lm] = accPV[u][reg];
  sjacc += __shfl_down(sjacc, 4);
  sjacc += __shfl_down(sjacc, 2);
  sjacc += __shfl_down(sjacc, 1);
  if (spart == 0) S2P[cid * N + j0 + srow] = sjacc;
}

// ---------- K6: e_Z reduce+normalize + autoencoder + MSE (16 rows/block, weights in LDS) ----------
#define AE_ROWS 16
__global__ __launch_bounds__(256) void k_ae(const float* __restrict__ x, const float* __restrict__ ezP,
                                            const float* __restrict__ S2P,
                                            const float* __restrict__ We1, const float* __restrict__ be1,
                                            const float* __restrict__ We2, const float* __restrict__ be2,
                                            const float* __restrict__ Wd1, const float* __restrict__ bd1,
                                            const float* __restrict__ Wd2, const float* __restrict__ bd2,
                                            float* __restrict__ out) {
  __shared__ float We1T[P][33];
  __shared__ float We2T[LDIM][33];
  __shared__ float Wd1T[LDIM][33];
  __shared__ float Wd2T[LDIM][129];
  __shared__ float ezs[AE_ROWS][P];
  __shared__ float h1s[AE_ROWS][LDIM], zbs[AE_ROWS][LDIM], h2s[AE_ROWS][LDIM];
  __shared__ float be1s[LDIM], be2s[LDIM], bd1s[LDIM], bd2s[P];
  __shared__ float s2s[AE_ROWS];
  const int tid = threadIdx.x;
  const int r0 = blockIdx.x * AE_ROWS;
  for (int idx = tid; idx < P * LDIM; idx += 256) {
    int o = idx >> 7, k = idx & 127;
    We1T[k][o] = We1[idx];
    int o2 = idx >> 5, k2 = idx & 31;
    Wd2T[k2][o2] = Wd2[idx];
  }
  for (int idx = tid; idx < LDIM * LDIM; idx += 256) {
    int o = idx >> 5, k = idx & 31;
    We2T[k][o] = We2[idx];
    Wd1T[k][o] = Wd1[idx];
  }
  if (tid < LDIM) { be1s[tid] = be1[tid]; be2s[tid] = be2[tid]; bd1s[tid] = bd1[tid]; }
  if (tid < P) bd2s[tid] = bd2[tid];
  if (tid < AE_ROWS) {
    float s = 0.0f;
#pragma unroll
    for (int c = 0; c < CHUNKS; ++c) s += S2P[c * N + r0 + tid];
    s2s[tid] = s;
  }
  __syncthreads();
  for (int idx = tid; idx < AE_ROWS * P; idx += 256) {
    int r = idx >> 7, col = idx & 127;
    int row = r0 + r;
    float es = 0.0f;
#pragma unroll
    for (int c = 0; c < CHUNKS; ++c) es += ezP[((size_t)c * N + row) * P + col];
    float xv = x[(size_t)row * P + col];
    ezs[r][col] = (s2s[r] > 0.0f) ? (es / s2s[r]) : xv;
  }
  __syncthreads();
  {
    const int o = tid & 31, rh = tid >> 5;
#pragma unroll
    for (int rr = 0; rr < 2; rr++) {
      int r = rh + rr * 8;
      float a = be1s[o];
#pragma unroll 8
      for (int k = 0; k < P; k++) a = fmaf(We1T[k][o], ezs[r][k], a);
      h1s[r][o] = geluf(a);
    }
  }
  __syncthreads();
  {
    const int o = tid & 31, rh = tid >> 5;
#pragma unroll
    for (int rr = 0; rr < 2; rr++) {
      int r = rh + rr * 8;
      float a = be2s[o];
#pragma unroll
      for (int k = 0; k < LDIM; k++) a = fmaf(We2T[k][o], h1s[r][k], a);
      zbs[r][o] = a;
    }
  }
  __syncthreads();
  {
    const int o = tid & 31, rh = tid >> 5;
#pragma unroll
    for (int rr = 0; rr < 2; rr++) {
      int r = rh + rr * 8;
      float a = bd1s[o];
#pragma unroll
      for (int k = 0; k < LDIM; k++) a = fmaf(Wd1T[k][o], zbs[r][k], a);
      h2s[r][o] = geluf(a);
    }
  }
  __syncthreads();
  {
    const int o = tid & 127, rh = tid >> 7;
    float part = 0.0f;
#pragma unroll
    for (int rr = 0; rr < 8; rr++) {
      int r = rh + rr * 2;
      int row = r0 + r;
      float a = bd2s[o];
#pragma unroll
      for (int k = 0; k < LDIM; k++) a = fmaf(Wd2T[k][o], h2s[r][k], a);
      float xh = 1.0f / (1.0f + expf(-a));
      float diff = x[(size_t)row * P + o] - xh;
      part = fmaf(diff, diff, part);
    }
#pragma unroll
    for (int off = 32; off > 0; off >>= 1) part += __shfl_down(part, off);
    if ((tid & 63) == 0) atomicAdd(out, part * (1.0f / ((float)N * (float)P)));
  }
}

extern "C" void kernel_launch(void* const* d_in, const int* in_sizes, int n_in,
                              void* d_out, int out_size, void* d_ws, size_t ws_size,
                              hipStream_t stream) {
  const float* x   = (const float*)d_in[0];
  const float* r0  = (const float*)d_in[1];
  const float* r1  = (const float*)d_in[2];
  const float* r2  = (const float*)d_in[3];
  const float* We1 = (const float*)d_in[4];
  const float* be1 = (const float*)d_in[5];
  const float* We2 = (const float*)d_in[6];
  const float* be2 = (const float*)d_in[7];
  const float* Wd1 = (const float*)d_in[8];
  const float* bd1 = (const float*)d_in[9];
  const float* Wd2 = (const float*)d_in[10];
  const float* bd2 = (const float*)d_in[11];
  float* out = (float*)d_out;

  char* base = (char*)d_ws;
  size_t off = 0;
  u16* xb  = (u16*)(base + off); off += (size_t)N * P * 2;
  u16* xbT = (u16*)(base + off); off += (size_t)N * P * 2;
  u16* Ub  = (u16*)(base + off); off += (size_t)N * P * 2;
  float* muP = (float*)(base + off); off += (size_t)CHUNKS * N * P * 4;
  float* ezP = (float*)(base + off); off += (size_t)CHUNKS * N * P * 4;
  float* S1P = (float*)(base + off); off += (size_t)CHUNKS * N * 4;
  float* S2P = (float*)(base + off); off += (size_t)CHUNKS * N * 4;
  float* x2  = (float*)(base + off); off += (size_t)N * 4;
  u32* mdb   = (u32*)(base + off); off += 4;  // zeroed together with x2
  float* u2  = (float*)(base + off); off += (size_t)N * 4;
  float* cjv = (float*)(base + off); off += (size_t)N * 4;

  const int zcnt = N + 1;  // x2 + mdb
  hipLaunchKernelGGL(k_init, dim3((zcnt + 255) / 256), dim3(256), 0, stream, x2, zcnt, out);
  hipLaunchKernelGGL(k_prep, dim3(N / 32, P / 32), dim3(256), 0, stream, x, xb, xbT, x2);
  hipLaunchKernelGGL(k_grammax, dim3(N / 64, CHUNKS), dim3(512), 0, stream, xb, x2, mdb);
  hipLaunchKernelGGL(k_alpha, dim3(N / 64, CHUNKS), dim3(512), 0, stream, xb, xbT, x2, muP, S1P, r0, mdb);
  hipLaunchKernelGGL(k_finU, dim3(N), dim3(128), 0, stream, x, xb, muP, S1P, Ub, u2, cjv);
  hipLaunchKernelGGL(k_betaez, dim3(N / 64, CHUNKS), dim3(512), 0, stream, xb, Ub, xbT, x2, u2, cjv, ezP, S2P, r1, r2, mdb);
  hipLaunchKernelGGL(k_ae, dim3(N / AE_ROWS), dim3(256), 0, stream, x, ezP, S2P, We1, be1, We2, be2, Wd1, bd1, Wd2, bd2, out);
}

// Round 7
// 186.904 us; speedup vs baseline: 1.9110x; 1.0755x over previous
//
#include <hip/hip_runtime.h>
#include <math.h>

#define N 4096
#define P 128
#define LDIM 32
#define CHUNKS 8
#define ITILES 4

typedef unsigned int u32;
typedef unsigned short u16;
typedef short s16x8 __attribute__((ext_vector_type(8)));
typedef float f32x4 __attribute__((ext_vector_type(4)));

// ---------- bf16 helpers (RNE) ----------
__device__ __forceinline__ u16 f2b(float f) {
  u32 u = __float_as_uint(f);
  u += 0x7fffu + ((u >> 16) & 1u);
  return (u16)(u >> 16);
}
__device__ __forceinline__ float b2f(u16 h) { return __uint_as_float(((u32)h) << 16); }

__device__ __forceinline__ float w2f(float d, float r) {
  if (d < 0.5f * r) return 1.0f;
  if (d < r) { float t = (2.0f * d - r) / r; float b = 1.0f - t * t; return b * b * b; }
  return 0.0f;
}
__device__ __forceinline__ float geluf(float a) {
  return 0.5f * a * (1.0f + erff(a * 0.70710678118654752f));
}

#define MFMA(a, b, c) __builtin_amdgcn_mfma_f32_16x16x32_bf16((a), (b), (c), 0, 0, 0)

// ---------- K0: zero mdb + out ----------
__global__ void k_init(u32* __restrict__ mdb, float* __restrict__ out) {
  if (threadIdx.x == 0) { *mdb = 0u; out[0] = 0.0f; }
}

// ---------- K1: xb = bf16(x), xbT = transpose, x2 full-row (no atomics) ----------
__global__ __launch_bounds__(256) void k_prep(const float* __restrict__ x, u16* __restrict__ xb,
                                              u16* __restrict__ xbT, float* __restrict__ x2) {
  __shared__ u16 tlT[128][40];  // [col][row], row-pad 40 -> 16B-aligned 16-element halves
  const int bi = blockIdx.x * 32;
  const int tid = threadIdx.x;
  const int r = tid >> 3, cg = (tid & 7) * 16;
  const float* src = &x[(size_t)(bi + r) * P + cg];
  float4 v0 = *(const float4*)(src + 0);
  float4 v1 = *(const float4*)(src + 4);
  float4 v2 = *(const float4*)(src + 8);
  float4 v3 = *(const float4*)(src + 12);
  u16 h[16];
  h[0] = f2b(v0.x); h[1] = f2b(v0.y); h[2] = f2b(v0.z); h[3] = f2b(v0.w);
  h[4] = f2b(v1.x); h[5] = f2b(v1.y); h[6] = f2b(v1.z); h[7] = f2b(v1.w);
  h[8] = f2b(v2.x); h[9] = f2b(v2.y); h[10] = f2b(v2.z); h[11] = f2b(v2.w);
  h[12] = f2b(v3.x); h[13] = f2b(v3.y); h[14] = f2b(v3.z); h[15] = f2b(v3.w);
  float s = 0.0f;
#pragma unroll
  for (int e = 0; e < 16; e++) { float f = b2f(h[e]); s = fmaf(f, f, s); }
  s += __shfl_down(s, 4); s += __shfl_down(s, 2); s += __shfl_down(s, 1);
  if ((tid & 7) == 0) x2[bi + r] = s;
  uint4 p0, p1;
  p0.x = (u32)h[0] | ((u32)h[1] << 16);  p0.y = (u32)h[2] | ((u32)h[3] << 16);
  p0.z = (u32)h[4] | ((u32)h[5] << 16);  p0.w = (u32)h[6] | ((u32)h[7] << 16);
  p1.x = (u32)h[8] | ((u32)h[9] << 16);  p1.y = (u32)h[10] | ((u32)h[11] << 16);
  p1.z = (u32)h[12] | ((u32)h[13] << 16); p1.w = (u32)h[14] | ((u32)h[15] << 16);
  *(uint4*)&xb[(size_t)(bi + r) * P + cg] = p0;
  *(uint4*)&xb[(size_t)(bi + r) * P + cg + 8] = p1;
#pragma unroll
  for (int e = 0; e < 16; e++) tlT[cg + e][r] = h[e];
  __syncthreads();
  const int c = tid >> 1, hh = tid & 1;
  uint4 q0 = *(const uint4*)&tlT[c][hh * 16];
  uint4 q1 = *(const uint4*)&tlT[c][hh * 16 + 8];
  *(uint4*)&xbT[(size_t)c * N + bi + hh * 16] = q0;
  *(uint4*)&xbT[(size_t)c * N + bi + hh * 16 + 8] = q1;
}

// ---------- K1b: anchor lower bound on max d2 (triangle ineq vs row 0) ----------
__global__ __launch_bounds__(128) void k_anchor(const u16* __restrict__ xb, const float* __restrict__ x2,
                                                u32* __restrict__ mdb) {
  const int i = blockIdx.x * 128 + threadIdx.x;
  const uint4* ra = (const uint4*)(xb + (size_t)i * P);
  const uint4* r0 = (const uint4*)xb;
  float dot = 0.0f;
#pragma unroll
  for (int q = 0; q < 16; ++q) {
    uint4 a = ra[q], b = r0[q];
    u32 aa[4] = {a.x, a.y, a.z, a.w}, bb[4] = {b.x, b.y, b.z, b.w};
#pragma unroll
    for (int e = 0; e < 4; e++) {
      dot = fmaf(b2f((u16)(aa[e] & 0xffffu)), b2f((u16)(bb[e] & 0xffffu)), dot);
      dot = fmaf(b2f((u16)(aa[e] >> 16)), b2f((u16)(bb[e] >> 16)), dot);
    }
  }
  float d2 = fmaxf(x2[i] + x2[0] - 2.0f * dot, 0.0f);
#pragma unroll
  for (int o = 32; o > 0; o >>= 1) d2 = fmaxf(d2, __shfl_down(d2, o));
  if ((threadIdx.x & 63) == 0) atomicMax(mdb, __float_as_uint(d2));
}

// ---------- K2: full max pairwise d2 — early-outs if anchor already proves md >= max(r) ----------
__global__ __launch_bounds__(512, 4) void k_grammax(const u16* __restrict__ xb, const float* __restrict__ x2,
                                                    u32* __restrict__ mdb,
                                                    const float* __restrict__ r0p, const float* __restrict__ r1p,
                                                    const float* __restrict__ r2p) {
  const float rmax = fmaxf(r0p[0], fmaxf(r1p[0], r2p[0])) * 1.02f;
  if (__uint_as_float(*mdb) >= rmax * rmax) return;  // min(r, md) == r for all r; exact value irrelevant
  __shared__ uint4 LA[1024];
  const int j0 = blockIdx.x * 64;
  const int cid = blockIdx.y;
  if (cid * 512 + 512 <= j0) return;
  const int tid = threadIdx.x;
  const int lane = tid & 63, w = tid >> 6;
  const int lm = lane & 15, quad = lane >> 4;
  {
    const uint4* g = (const uint4*)(xb + (size_t)j0 * P);
#pragma unroll
    for (int it = 0; it < 2; ++it) {
      int c = it * 512 + tid;
      int row = c >> 4, ch = c & 15;
      LA[row * 16 + (ch ^ (row & 7))] = g[c];
    }
  }
  float x2j[4][4];
#pragma unroll
  for (int u = 0; u < 4; u++)
#pragma unroll
    for (int reg = 0; reg < 4; reg++) x2j[u][reg] = x2[j0 + u * 16 + quad * 4 + reg];
  __syncthreads();
  float lmax = 0.0f;
  for (int t = 0; t < ITILES; ++t) {
    const int i0 = cid * 512 + t * 128;
    if (i0 + 128 <= j0) continue;
    f32x4 accG[4];
#pragma unroll
    for (int u = 0; u < 4; u++) accG[u] = {0.f, 0.f, 0.f, 0.f};
    const u16* gb = xb + (size_t)(i0 + w * 16 + lm) * P;
#pragma unroll
    for (int ks = 0; ks < 4; ++ks) {
      s16x8 bf = *(const s16x8*)(gb + ks * 32 + quad * 8);
      s16x8 af[4];
#pragma unroll
      for (int u = 0; u < 4; u++) { int m = u * 16 + lm; af[u] = *(const s16x8*)&LA[m * 16 + ((ks * 4 + quad) ^ (m & 7))]; }
#pragma unroll
      for (int u = 0; u < 4; u++) accG[u] = MFMA(af[u], bf, accG[u]);
    }
    float x2i = x2[i0 + w * 16 + lm];
#pragma unroll
    for (int u = 0; u < 4; u++)
#pragma unroll
      for (int reg = 0; reg < 4; reg++) lmax = fmaxf(lmax, x2j[u][reg] + x2i - 2.0f * accG[u][reg]);
  }
#pragma unroll
  for (int o = 32; o > 0; o >>= 1) lmax = fmaxf(lmax, __shfl_down(lmax, o));
  if (lane == 0) atomicMax(mdb, __float_as_uint(lmax));
}

// ---------- K3: fused alpha. Gram (i-rows from global, j from LDS) -> w1 -> W(LDS) -> PV + ones-MFMA S1 ----------
__global__ __launch_bounds__(512, 4) void k_alpha(const u16* __restrict__ xb, const u16* __restrict__ xbT,
                                                  const float* __restrict__ x2,
                                                  float* __restrict__ muP, float* __restrict__ S1P,
                                                  const float* __restrict__ r0p, const u32* __restrict__ mdb) {
  __shared__ uint4 LA[1024];     // xb_j 64x128 swizzled
  __shared__ u16 W16[64 * 136];  // W[j][i]
  const int j0 = blockIdx.x * 64, cid = blockIdx.y;
  const int tid = threadIdx.x;
  const int lane = tid & 63, w = tid >> 6;
  const int lm = lane & 15, quad = lane >> 4;
  {
    const uint4* g = (const uint4*)(xb + (size_t)j0 * P);
#pragma unroll
    for (int it = 0; it < 2; ++it) {
      int c = it * 512 + tid;
      int row = c >> 4, ch = c & 15;
      LA[row * 16 + (ch ^ (row & 7))] = g[c];
    }
  }
  const float mdf = sqrtf(fmaxf(__uint_as_float(*mdb), 1e-12f));
  const float re = fminf(r0p[0], mdf);
  const float re2 = re * re, inv_re2 = 1.0f / re2;
  float x2j[4];
#pragma unroll
  for (int v = 0; v < 4; v++) x2j[v] = x2[j0 + v * 16 + lm];
  f32x4 accPV[4], accS[4];
#pragma unroll
  for (int u = 0; u < 4; u++) { accPV[u] = {0.f, 0.f, 0.f, 0.f}; accS[u] = {0.f, 0.f, 0.f, 0.f}; }
  const s16x8 ones = {0x3F80, 0x3F80, 0x3F80, 0x3F80, 0x3F80, 0x3F80, 0x3F80, 0x3F80};
  __syncthreads();
  for (int t = 0; t < ITILES; ++t) {
    const int i0 = cid * 512 + t * 128;
    f32x4 accG[4];
#pragma unroll
    for (int v = 0; v < 4; v++) accG[v] = {0.f, 0.f, 0.f, 0.f};
    const u16* ga = xb + (size_t)(i0 + w * 16 + lm) * P;  // A rows = i
#pragma unroll
    for (int ks = 0; ks < 4; ++ks) {
      s16x8 af = *(const s16x8*)(ga + ks * 32 + quad * 8);
      s16x8 bf[4];
#pragma unroll
      for (int v = 0; v < 4; v++) { int m = v * 16 + lm; bf[v] = *(const s16x8*)&LA[m * 16 + ((ks * 4 + quad) ^ (m & 7))]; }
#pragma unroll
      for (int v = 0; v < 4; v++) accG[v] = MFMA(af, bf[v], accG[v]);
    }
    float4 x2iv = *(const float4*)&x2[i0 + w * 16 + quad * 4];  // i-stats (4 consecutive)
    const float xi[4] = {x2iv.x, x2iv.y, x2iv.z, x2iv.w};
    u16 wv4[4][4];
#pragma unroll
    for (int v = 0; v < 4; v++)
#pragma unroll
      for (int reg = 0; reg < 4; reg++) {
        float d2 = fmaxf(xi[reg] + x2j[v] - 2.0f * accG[v][reg], 1e-12f);
        float wt = 0.0f;
        if (d2 < re2) { float b = 1.0f - d2 * inv_re2; wt = b * b * b; }
        wv4[v][reg] = f2b(wt);
      }
    __syncthreads();  // prev tile's W16 readers done
#pragma unroll
    for (int v = 0; v < 4; v++) {
      ushort4 pk; pk.x = wv4[v][0]; pk.y = wv4[v][1]; pk.z = wv4[v][2]; pk.w = wv4[v][3];
      *(ushort4*)&W16[(v * 16 + lm) * 136 + w * 16 + quad * 4] = pk;
    }
    __syncthreads();
    const u16* gx = xbT + (size_t)(w * 16 + lm) * N + i0;  // B cols = p
#pragma unroll
    for (int ks = 0; ks < 4; ++ks) {
      s16x8 bx = *(const s16x8*)(gx + ks * 32 + quad * 8);
      s16x8 aw[4];
#pragma unroll
      for (int u = 0; u < 4; u++) { int m = u * 16 + lm; aw[u] = *(const s16x8*)&W16[m * 136 + ks * 32 + quad * 8]; }
#pragma unroll
      for (int u = 0; u < 4; u++) accPV[u] = MFMA(aw[u], bx, accPV[u]);
      if (w == 0) {
#pragma unroll
        for (int u = 0; u < 4; u++) accS[u] = MFMA(aw[u], ones, accS[u]);
      }
    }
  }
  float* mu = muP + (size_t)cid * N * P;
#pragma unroll
  for (int u = 0; u < 4; u++)
#pragma unroll
    for (int reg = 0; reg < 4; reg++)
      mu[(size_t)(j0 + u * 16 + quad * 4 + reg) * P + w * 16 + lm] = accPV[u][reg];
  if (w == 0 && lm == 0) {
#pragma unroll
    for (int u = 0; u < 4; u++)
#pragma unroll
      for (int reg = 0; reg < 4; reg++)
        S1P[cid * N + j0 + u * 16 + quad * 4 + reg] = accS[u][reg];
  }
}

// ---------- K4: U finalize (reduce muP partials), Ub=bf16(U), u2,cj from bf16 ----------
__global__ __launch_bounds__(128) void k_finU(const float* __restrict__ x, const u16* __restrict__ xb,
                                              const float* __restrict__ muP, const float* __restrict__ S1P,
                                              u16* __restrict__ Ub, float* __restrict__ u2, float* __restrict__ cj) {
  const int j = blockIdx.x, t = threadIdx.x;
  float ssum = 0.0f, msum = 0.0f;
#pragma unroll
  for (int c = 0; c < CHUNKS; ++c) {
    ssum += S1P[c * N + j];
    msum += muP[((size_t)c * N + j) * P + t];
  }
  float xv = x[(size_t)j * P + t];
  float uval = 0.0f;
  if (ssum > 0.0f) uval = xv - msum / ssum;
  u16 ub = f2b(uval);
  Ub[(size_t)j * P + t] = ub;
  float uf = b2f(ub);
  float xbf = b2f(xb[(size_t)j * P + t]);
  float a = uf * uf, b = xbf * uf;
#pragma unroll
  for (int o = 32; o > 0; o >>= 1) { a += __shfl_down(a, o); b += __shfl_down(b, o); }
  __shared__ float ra[2], rb[2];
  if ((t & 63) == 0) { ra[t >> 6] = a; rb[t >> 6] = b; }
  __syncthreads();
  if (t == 0) { u2[j] = ra[0] + ra[1]; cj[j] = rb[0] + rb[1]; }
}

// ---------- K5: fused beta. Two Grams -> w2 -> W(LDS) -> PV + ones-MFMA S2. cj folded into accP init ----------
__global__ __launch_bounds__(512, 4) void k_betaez(const u16* __restrict__ xb, const u16* __restrict__ Ub,
                                                   const u16* __restrict__ xbT,
                                                   const float* __restrict__ x2, const float* __restrict__ u2,
                                                   const float* __restrict__ cj,
                                                   float* __restrict__ ezP, float* __restrict__ S2P,
                                                   const float* __restrict__ r1p, const float* __restrict__ r2p,
                                                   const u32* __restrict__ mdb) {
  __shared__ uint4 LA[1024];
  __shared__ uint4 LU[1024];
  __shared__ u16 W16[64 * 136];
  const int j0 = blockIdx.x * 64, cid = blockIdx.y;
  const int tid = threadIdx.x;
  const int lane = tid & 63, w = tid >> 6;
  const int lm = lane & 15, quad = lane >> 4;
  {
    const uint4* ga = (const uint4*)(xb + (size_t)j0 * P);
    const uint4* gu = (const uint4*)(Ub + (size_t)j0 * P);
#pragma unroll
    for (int it = 0; it < 2; ++it) {
      int c = it * 512 + tid;
      int row = c >> 4, ch = c & 15;
      int sw = row * 16 + (ch ^ (row & 7));
      LA[sw] = ga[c];
      LU[sw] = gu[c];
    }
  }
  const float mdf = sqrtf(fmaxf(__uint_as_float(*mdb), 1e-12f));
  const float r1e = fminf(r1p[0], mdf), r2e = fminf(r2p[0], mdf);
  float x2j[4], u2j[4], ncj[4];
#pragma unroll
  for (int v = 0; v < 4; v++) {
    int jj = j0 + v * 16 + lm;
    x2j[v] = x2[jj]; u2j[v] = u2[jj]; ncj[v] = -cj[jj];
  }
  f32x4 accPV[4], accS[4];
#pragma unroll
  for (int u = 0; u < 4; u++) { accPV[u] = {0.f, 0.f, 0.f, 0.f}; accS[u] = {0.f, 0.f, 0.f, 0.f}; }
  const s16x8 ones = {0x3F80, 0x3F80, 0x3F80, 0x3F80, 0x3F80, 0x3F80, 0x3F80, 0x3F80};
  __syncthreads();
  for (int t = 0; t < ITILES; ++t) {
    const int i0 = cid * 512 + t * 128;
    f32x4 accG[4], accP[4];
#pragma unroll
    for (int v = 0; v < 4; v++) {
      accG[v] = {0.f, 0.f, 0.f, 0.f};
      accP[v] = {ncj[v], ncj[v], ncj[v], ncj[v]};  // ps = x_i.U_j - cj_j via C-init
    }
    const u16* ga = xb + (size_t)(i0 + w * 16 + lm) * P;
#pragma unroll
    for (int ks = 0; ks < 4; ++ks) {
      s16x8 af = *(const s16x8*)(ga + ks * 32 + quad * 8);
      s16x8 bf[4], bu[4];
#pragma unroll
      for (int v = 0; v < 4; v++) {
        int m = v * 16 + lm;
        int off = m * 16 + ((ks * 4 + quad) ^ (m & 7));
        bf[v] = *(const s16x8*)&LA[off];
        bu[v] = *(const s16x8*)&LU[off];
      }
#pragma unroll
      for (int v = 0; v < 4; v++) {
        accG[v] = MFMA(af, bf[v], accG[v]);
        accP[v] = MFMA(af, bu[v], accP[v]);
      }
    }
    float4 x2iv = *(const float4*)&x2[i0 + w * 16 + quad * 4];
    const float xi[4] = {x2iv.x, x2iv.y, x2iv.z, x2iv.w};
    u16 wv4[4][4];
#pragma unroll
    for (int v = 0; v < 4; v++)
#pragma unroll
      for (int reg = 0; reg < 4; reg++) {
        float d2 = fmaxf(xi[reg] + x2j[v] - 2.0f * accG[v][reg], 1e-12f);
        float ps = accP[v][reg];
        float du2 = fmaxf(ps * ps * u2j[v], 1e-6f);
        float dv = sqrtf(fmaxf(d2 - du2, 1e-6f));
        float du = sqrtf(du2);
        wv4[v][reg] = f2b(w2f(dv, r1e) * w2f(du, r2e));
      }
    __syncthreads();
#pragma unroll
    for (int v = 0; v < 4; v++) {
      ushort4 pk; pk.x = wv4[v][0]; pk.y = wv4[v][1]; pk.z = wv4[v][2]; pk.w = wv4[v][3];
      *(ushort4*)&W16[(v * 16 + lm) * 136 + w * 16 + quad * 4] = pk;
    }
    __syncthreads();
    const u16* gx = xbT + (size_t)(w * 16 + lm) * N + i0;
#pragma unroll
    for (int ks = 0; ks < 4; ++ks) {
      s16x8 bx = *(const s16x8*)(gx + ks * 32 + quad * 8);
      s16x8 aw[4];
#pragma unroll
      for (int u = 0; u < 4; u++) { int m = u * 16 + lm; aw[u] = *(const s16x8*)&W16[m * 136 + ks * 32 + quad * 8]; }
#pragma unroll
      for (int u = 0; u < 4; u++) accPV[u] = MFMA(aw[u], bx, accPV[u]);
      if (w == 0) {
#pragma unroll
        for (int u = 0; u < 4; u++) accS[u] = MFMA(aw[u], ones, accS[u]);
      }
    }
  }
  float* ez = ezP + (size_t)cid * N * P;
#pragma unroll
  for (int u = 0; u < 4; u++)
#pragma unroll
    for (int reg = 0; reg < 4; reg++)
      ez[(size_t)(j0 + u * 16 + quad * 4 + reg) * P + w * 16 + lm] = accPV[u][reg];
  if (w == 0 && lm == 0) {
#pragma unroll
    for (int u = 0; u < 4; u++)
#pragma unroll
      for (int reg = 0; reg < 4; reg++)
        S2P[cid * N + j0 + u * 16 + quad * 4 + reg] = accS[u][reg];
  }
}

// ---------- K6: e_Z reduce+normalize + autoencoder + MSE ----------
#define AE_ROWS 16
__global__ __launch_bounds__(256) void k_ae(const float* __restrict__ x, const float* __restrict__ ezP,
                                            const float* __restrict__ S2P,
                                            const float* __restrict__ We1, const float* __restrict__ be1,
                                            const float* __restrict__ We2, const float* __restrict__ be2,
                                            const float* __restrict__ Wd1, const float* __restrict__ bd1,
                                            const float* __restrict__ Wd2, const float* __restrict__ bd2,
                                            float* __restrict__ out) {
  __shared__ float We1T[P][33];
  __shared__ float We2T[LDIM][33];
  __shared__ float Wd1T[LDIM][33];
  __shared__ float Wd2T[LDIM][129];
  __shared__ float ezs[AE_ROWS][P];
  __shared__ float h1s[AE_ROWS][LDIM], zbs[AE_ROWS][LDIM], h2s[AE_ROWS][LDIM];
  __shared__ float be1s[LDIM], be2s[LDIM], bd1s[LDIM], bd2s[P];
  __shared__ float s2s[AE_ROWS];
  const int tid = threadIdx.x;
  const int r0 = blockIdx.x * AE_ROWS;
  for (int idx = tid; idx < P * LDIM; idx += 256) {
    int o = idx >> 7, k = idx & 127;
    We1T[k][o] = We1[idx];
    int o2 = idx >> 5, k2 = idx & 31;
    Wd2T[k2][o2] = Wd2[idx];
  }
  for (int idx = tid; idx < LDIM * LDIM; idx += 256) {
    int o = idx >> 5, k = idx & 31;
    We2T[k][o] = We2[idx];
    Wd1T[k][o] = Wd1[idx];
  }
  if (tid < LDIM) { be1s[tid] = be1[tid]; be2s[tid] = be2[tid]; bd1s[tid] = bd1[tid]; }
  if (tid < P) bd2s[tid] = bd2[tid];
  if (tid < AE_ROWS) {
    float s = 0.0f;
#pragma unroll
    for (int c = 0; c < CHUNKS; ++c) s += S2P[c * N + r0 + tid];
    s2s[tid] = s;
  }
  __syncthreads();
  for (int idx = tid; idx < AE_ROWS * P; idx += 256) {
    int r = idx >> 7, col = idx & 127;
    int row = r0 + r;
    float es = 0.0f;
#pragma unroll
    for (int c = 0; c < CHUNKS; ++c) es += ezP[((size_t)c * N + row) * P + col];
    float xv = x[(size_t)row * P + col];
    ezs[r][col] = (s2s[r] > 0.0f) ? (es / s2s[r]) : xv;
  }
  __syncthreads();
  {
    const int o = tid & 31, rh = tid >> 5;
#pragma unroll
    for (int rr = 0; rr < 2; rr++) {
      int r = rh + rr * 8;
      float a = be1s[o];
#pragma unroll 8
      for (int k = 0; k < P; k++) a = fmaf(We1T[k][o], ezs[r][k], a);
      h1s[r][o] = geluf(a);
    }
  }
  __syncthreads();
  {
    const int o = tid & 31, rh = tid >> 5;
#pragma unroll
    for (int rr = 0; rr < 2; rr++) {
      int r = rh + rr * 8;
      float a = be2s[o];
#pragma unroll
      for (int k = 0; k < LDIM; k++) a = fmaf(We2T[k][o], h1s[r][k], a);
      zbs[r][o] = a;
    }
  }
  __syncthreads();
  {
    const int o = tid & 31, rh = tid >> 5;
#pragma unroll
    for (int rr = 0; rr < 2; rr++) {
      int r = rh + rr * 8;
      float a = bd1s[o];
#pragma unroll
      for (int k = 0; k < LDIM; k++) a = fmaf(Wd1T[k][o], zbs[r][k], a);
      h2s[r][o] = geluf(a);
    }
  }
  __syncthreads();
  {
    const int o = tid & 127, rh = tid >> 7;
    float part = 0.0f;
#pragma unroll
    for (int rr = 0; rr < 8; rr++) {
      int r = rh + rr * 2;
      int row = r0 + r;
      float a = bd2s[o];
#pragma unroll
      for (int k = 0; k < LDIM; k++) a = fmaf(Wd2T[k][o], h2s[r][k], a);
      float xh = 1.0f / (1.0f + expf(-a));
      float diff = x[(size_t)row * P + o] - xh;
      part = fmaf(diff, diff, part);
    }
#pragma unroll
    for (int off = 32; off > 0; off >>= 1) part += __shfl_down(part, off);
    if ((tid & 63) == 0) atomicAdd(out, part * (1.0f / ((float)N * (float)P)));
  }
}

extern "C" void kernel_launch(void* const* d_in, const int* in_sizes, int n_in,
                              void* d_out, int out_size, void* d_ws, size_t ws_size,
                              hipStream_t stream) {
  const float* x   = (const float*)d_in[0];
  const float* r0  = (const float*)d_in[1];
  const float* r1  = (const float*)d_in[2];
  const float* r2  = (const float*)d_in[3];
  const float* We1 = (const float*)d_in[4];
  const float* be1 = (const float*)d_in[5];
  const float* We2 = (const float*)d_in[6];
  const float* be2 = (const float*)d_in[7];
  const float* Wd1 = (const float*)d_in[8];
  const float* bd1 = (const float*)d_in[9];
  const float* Wd2 = (const float*)d_in[10];
  const float* bd2 = (const float*)d_in[11];
  float* out = (float*)d_out;

  char* base = (char*)d_ws;
  size_t off = 0;
  u16* xb  = (u16*)(base + off); off += (size_t)N * P * 2;
  u16* xbT = (u16*)(base + off); off += (size_t)N * P * 2;
  u16* Ub  = (u16*)(base + off); off += (size_t)N * P * 2;
  float* muP = (float*)(base + off); off += (size_t)CHUNKS * N * P * 4;
  float* ezP = (float*)(base + off); off += (size_t)CHUNKS * N * 4 * P / 4 * 4;  // CHUNKS*N*P*4
  float* S1P = (float*)(base + off); off += (size_t)CHUNKS * N * 4;
  float* S2P = (float*)(base + off); off += (size_t)CHUNKS * N * 4;
  float* x2  = (float*)(base + off); off += (size_t)N * 4;
  u32* mdb   = (u32*)(base + off); off += 4;
  float* u2  = (float*)(base + off); off += (size_t)N * 4;
  float* cjv = (float*)(base + off); off += (size_t)N * 4;

  hipLaunchKernelGGL(k_init, dim3(1), dim3(64), 0, stream, mdb, out);
  hipLaunchKernelGGL(k_prep, dim3(N / 32), dim3(256), 0, stream, x, xb, xbT, x2);
  hipLaunchKernelGGL(k_anchor, dim3(N / 128), dim3(128), 0, stream, xb, x2, mdb);
  hipLaunchKernelGGL(k_grammax, dim3(N / 64, CHUNKS), dim3(512), 0, stream, xb, x2, mdb, r0, r1, r2);
  hipLaunchKernelGGL(k_alpha, dim3(N / 64, CHUNKS), dim3(512), 0, stream, xb, xbT, x2, muP, S1P, r0, mdb);
  hipLaunchKernelGGL(k_finU, dim3(N), dim3(128), 0, stream, x, xb, muP, S1P, Ub, u2, cjv);
  hipLaunchKernelGGL(k_betaez, dim3(N / 64, CHUNKS), dim3(512), 0, stream, xb, Ub, xbT, x2, u2, cjv, ezP, S2P, r1, r2, mdb);
  hipLaunchKernelGGL(k_ae, dim3(N / AE_ROWS), dim3(256), 0, stream, x, ezP, S2P, We1, be1, We2, be2, Wd1, bd1, Wd2, bd2, out);
}